// Round 21
// baseline (161.242 us; speedup 1.0000x reference)
//
#include <hip/hip_runtime.h>
#include <hip/hip_bf16.h>
#include <math.h>

#define SS   1024
#define DM   1024
#define NH   16
#define DKH  64
#define NB   4
#define NBH  64

typedef unsigned short ush;
typedef unsigned int uint32;
typedef __attribute__((ext_vector_type(8))) short bf8_t;   // 8 bf16 = 4 VGPR
typedef __attribute__((ext_vector_type(4))) float f32x4;
#define MFMA16(a,b,c) __builtin_amdgcn_mfma_f32_16x16x32_bf16((a),(b),(c),0,0,0)

__device__ __forceinline__ ush f2bf(float x){ return __bfloat16_as_ushort(__float2bfloat16(x)); }
__device__ __forceinline__ uint32 pk2(float a, float b){
  return (uint32)f2bf(a) | ((uint32)f2bf(b) << 16);
}
// [rows][64]-ush tile, XOR swizzle on 16B chunks
__device__ __forceinline__ int swz8(int row, int chunk){
  return row*64 + (((chunk) ^ (row & 7)) << 3);
}
union U4B8 { uint4 u; bf8_t b; };

// ---- weight convert: W (K x N) fp32 -> Wt (N x K) bf16 hi only
__global__ void wconv4(const float* __restrict__ W0, const float* __restrict__ W1,
                       const float* __restrict__ W2, const float* __restrict__ W3,
                       ush* __restrict__ H0, ush* __restrict__ H1,
                       ush* __restrict__ H2, ush* __restrict__ H3)
{
  __shared__ float T[32][33];
  const int tx = threadIdx.x, ty = threadIdx.y;    // (32,8)
  const int z = blockIdx.z;
  const float* W = (z==0)?W0:(z==1)?W1:(z==2)?W2:W3;
  ush* H = (z==0)?H0:(z==1)?H1:(z==2)?H2:H3;
  const int k0 = blockIdx.y*32, n0 = blockIdx.x*32;
  #pragma unroll
  for (int i = 0; i < 4; ++i){
    int r = ty + 8*i;
    T[r][tx] = W[(size_t)(k0 + r)*DM + n0 + tx];
  }
  __syncthreads();
  #pragma unroll
  for (int i = 0; i < 4; ++i){
    int r = ty + 8*i;              // n-local
    H[(size_t)(n0 + r)*DM + k0 + tx] = f2bf(T[tx][r]);
  }
}

// ---- fused Q/K/V projection (xconv folded in): BK=32, 1-term (W hi).
// A staged as FP32 via global_load_lds (pre-swizzled source), converted to
// bf16 at fragment-load time. B staged bf16 as before. LDS = 48 KB dbuf.
// Q/K out plain bf16 (b*16+h, s, dk); V out bf16 transposed (b*16+h, dk, s).
__global__ __launch_bounds__(256) void proj_qkv(
    const float* __restrict__ xq, const float* __restrict__ xk, const float* __restrict__ xv,
    const ush* __restrict__ Wqh, const ush* __restrict__ Wkh, const ush* __restrict__ Wvh,
    const float* __restrict__ bq, const float* __restrict__ bk,
    const float* __restrict__ bv,
    ush* __restrict__ Qb, ush* __restrict__ Kb, ush* __restrict__ Vt)
{
  // layout (bytes): buf = [A f32 16384 | B bf16 8192] x2 = 49152 B
  __shared__ ush SMEM[24576];
  float* SMEMf = (float*)SMEM;

  const int fid = blockIdx.x;
  const int glob = (fid & 7)*96 + (fid >> 3);  // XCD-contiguous chunks of 96
  const int z = glob >> 8, rem = glob & 255;
  const int m0 = (rem >> 3) * 128, n0 = (rem & 7) * 128;

  const float* A = (z==0) ? xq  : (z==1) ? xk  : xv;
  const ush* Bh  = (z==0) ? Wqh : (z==1) ? Wkh : Wvh;

  const int tid = threadIdx.x;
  const int lane = tid & 63, w = tid >> 6;
  const int c = lane & 15, g = lane >> 4;
  const int wr = w >> 1, wc = w & 1;

  f32x4 acc[4][4];
  #pragma unroll
  for (int i = 0; i < 4; ++i)
    #pragma unroll
    for (int j = 0; j < 4; ++j) acc[i][j] = (f32x4){0.f,0.f,0.f,0.f};

  // ---- A staging map (fp32, [128][32] f32 rows, XOR-swizzled 16B chunks):
  // wave w instr i covers phys rows w*32+i*8 .. +8; lane l -> row +(l>>3),
  // chunk j=l&7; source chunk = j ^ (row&7) = j ^ (l>>3).
  const int arowg = lane >> 3;                 // 0..7
  const int asw   = ((lane & 7) ^ arowg) << 2; // float offset of source chunk
  const float* Aab = A + (size_t)m0*DM;

  // ---- B staging map (bf16, paired-row [64][64] ush, as before)
  const int prow0 = w*16 + (lane >> 3), prow1 = prow0 + 8;
  const int jj = lane & 7;
  const int sg0 = jj ^ (prow0 & 7), sg1 = jj ^ (prow1 & 7);
  const size_t boff0 = (size_t)(2*prow0 + (sg0 >> 2))*DM + (sg0 & 3)*8;
  const size_t boff1 = (size_t)(2*prow1 + (sg1 >> 2))*DM + (sg1 & 3)*8;
  const ush* Bhb = Bh + (size_t)n0*DM;
  const int lb0 = w*1024, lb1 = w*1024 + 512;  // ush, within B region

#define GLLF(GP, FIDX) __builtin_amdgcn_global_load_lds( \
    (const __attribute__((address_space(1))) unsigned int*)(GP), \
    (__attribute__((address_space(3))) unsigned int*)(&SMEMf[FIDX]), 16, 0, 0)
#define GLLU(GP, UIDX) __builtin_amdgcn_global_load_lds( \
    (const __attribute__((address_space(1))) unsigned int*)(GP), \
    (__attribute__((address_space(3))) unsigned int*)(&SMEM[UIDX]), 16, 0, 0)

  // BUFO_F: float index of A region; BUFO_U: ush index of B region
#define ISSUE_PROJ(BUFO_F, BUFO_U, KT) do{ \
    GLLF(Aab + (size_t)(w*32 + 0*8 + arowg)*DM + asw + (KT), (BUFO_F) + w*1024 + 0*256); \
    GLLF(Aab + (size_t)(w*32 + 1*8 + arowg)*DM + asw + (KT), (BUFO_F) + w*1024 + 1*256); \
    GLLF(Aab + (size_t)(w*32 + 2*8 + arowg)*DM + asw + (KT), (BUFO_F) + w*1024 + 2*256); \
    GLLF(Aab + (size_t)(w*32 + 3*8 + arowg)*DM + asw + (KT), (BUFO_F) + w*1024 + 3*256); \
    GLLU(Bhb + boff0 + (KT), (BUFO_U) + lb0); \
    GLLU(Bhb + boff1 + (KT), (BUFO_U) + lb1); \
  }while(0)

  const int csw = (((4*(c & 1) + g) ^ ((c >> 1) & 7)) << 3);
  const int cs0 = ((2*g)     ^ (c & 7)) << 2;   // A frag source chunks (f32)
  const int cs1 = ((2*g + 1) ^ (c & 7)) << 2;

  ISSUE_PROJ(0, 8192, 0);
  int cur = 0;
  for (int kt = 0; kt < DM; kt += 32){
    __syncthreads();                       // drains vmcnt -> buf[cur] ready
    if (kt + 32 < DM) ISSUE_PROJ((cur ^ 1)*6144, (cur ^ 1)*12288 + 8192, kt + 32);

    const float* Afp = SMEMf + cur*6144;
    const ush*   Bhs = SMEM + cur*12288 + 8192;

    bf8_t a_h[4];
    #pragma unroll
    for (int fm = 0; fm < 4; ++fm){
      const int arow = 64*wr + 16*fm + c;
      float av[8];
      *(float4*)&av[0] = *(const float4*)&Afp[arow*32 + cs0];
      *(float4*)&av[4] = *(const float4*)&Afp[arow*32 + cs1];
      U4B8 t;
      t.u = (uint4){pk2(av[0],av[1]), pk2(av[2],av[3]),
                    pk2(av[4],av[5]), pk2(av[6],av[7])};
      a_h[fm] = t.b;
    }
    __builtin_amdgcn_s_setprio(1);
    #pragma unroll
    for (int fn = 0; fn < 4; ++fn){
      bf8_t b_h = *(const bf8_t*)&Bhs[(32*wc + 8*fn + (c>>1))*64 + csw];
      #pragma unroll
      for (int fm = 0; fm < 4; ++fm)
        acc[fm][fn] = MFMA16(a_h[fm], b_h, acc[fm][fn]);
    }
    __builtin_amdgcn_s_setprio(0);
    cur ^= 1;
  }
#undef ISSUE_PROJ
#undef GLLF
#undef GLLU

  if (z < 2){
    ush* O = (z==0) ? Qb : Kb;
    const float* bias = (z==0) ? bq : bk;
    #pragma unroll
    for (int fm = 0; fm < 4; ++fm){
      #pragma unroll
      for (int fn = 0; fn < 4; ++fn){
        const int col = n0 + 64*wc + 16*fn + c;
        const float bb = bias[col];
        const int row0 = m0 + 64*wr + 16*fm + 4*g;
        const int hd = col >> 6, d = col & 63;
        #pragma unroll
        for (int r = 0; r < 4; ++r){
          const int row = row0 + r;
          const int b = row >> 10, s = row & 1023;
          O[((size_t)(b*NH + hd)*SS + s)*DKH + d] = f2bf(acc[fm][fn][r] + bb);
        }
      }
    }
  } else {
    // V: transpose wave's 64(s) x 64(d) sub-tile through LDS -> coalesced (d,s)
    __syncthreads();                      // all waves done reading staging LDS
    ush* Vep = SMEM + w*4224;             // 64 rows(d) x 66 cols(s)
    #pragma unroll
    for (int fm = 0; fm < 4; ++fm){
      #pragma unroll
      for (int fn = 0; fn < 4; ++fn){
        const float bb = bv[n0 + 64*wc + 16*fn + c];
        #pragma unroll
        for (int r = 0; r < 4; ++r)
          Vep[(16*fn + c)*66 + 16*fm + 4*g + r] = f2bf(acc[fm][fn][r] + bb);
      }
    }
    const int b = m0 >> 10;
    const int s0 = (m0 & 1023) + 64*wr;
    const int hd = (n0 >> 6) + wc;
    const size_t vbase = ((size_t)(b*NH + hd))*DKH*SS;
    #pragma unroll
    for (int it = 0; it < 8; ++it){
      const int dr = 8*it + (lane >> 3);
      const int sc = (lane & 7)*8;
      uint4 vv = *(const uint4*)&Vep[dr*66 + sc];
      *(uint4*)&Vt[vbase + (size_t)dr*SS + s0 + sc] = vv;
    }
  }
}

// ---- output projection: C = A(bf16) @ Wo^T + bo, 128x64 tile, paired-row LDS
__global__ __launch_bounds__(256) void gemm_out(
    const ush* __restrict__ Abf, const ush* __restrict__ Bth,
    const float* __restrict__ bias, float* __restrict__ outf)
{
  __shared__ ush As[4096], Bs[2048];

  const int fid = blockIdx.x;
  const int glob = (fid & 7)*64 + (fid >> 3);
  const int m0 = (glob >> 4)*128, n0 = (glob & 15)*64;

  const int tid = threadIdx.x;
  const int lane = tid & 63, w = tid >> 6;
  const int c = lane & 15, g = lane >> 4;
  const int wr = w >> 1, wc = w & 1;

  f32x4 acc[4][2];
  #pragma unroll
  for (int i = 0; i < 4; ++i){ acc[i][0] = (f32x4){0,0,0,0}; acc[i][1] = (f32x4){0,0,0,0}; }

  const int prow = tid >> 3, ci = tid & 7;
  const int lr   = 2*prow + (ci >> 2);
  const int koff = (ci & 3) << 3;
  const int ws0  = prow*64 + ((ci ^ (prow & 7)) << 3);
  const int ws1  = ws0 + 32*64;
  const int csw  = (((4*(c & 1) + g) ^ ((c >> 1) & 7)) << 3);

  uint4 ar0, ar1, brr;
  #define ISSUE_OUT(KT) do{ \
    ar0 = *(const uint4*)(Abf + (size_t)(m0 + lr)*DM + (KT) + koff); \
    ar1 = *(const uint4*)(Abf + (size_t)(m0 + lr + 64)*DM + (KT) + koff); \
    brr = *(const uint4*)(Bth + (size_t)(n0 + lr)*DM + (KT) + koff); \
  }while(0)

  ISSUE_OUT(0);
  for (int kt = 0; kt < DM; kt += 32){
    *(uint4*)&As[ws0] = ar0;
    *(uint4*)&As[ws1] = ar1;
    if (lr < 64) *(uint4*)&Bs[ws0] = brr;
    __syncthreads();
    if (kt + 32 < DM) ISSUE_OUT(kt + 32);

    bf8_t a_h[4];
    #pragma unroll
    for (int fm = 0; fm < 4; ++fm)
      a_h[fm] = *(const bf8_t*)&As[(32*wr + 8*fm + (c>>1))*64 + csw];
    #pragma unroll
    for (int fn = 0; fn < 2; ++fn){
      bf8_t b_h = *(const bf8_t*)&Bs[(16*wc + 8*fn + (c>>1))*64 + csw];
      #pragma unroll
      for (int fm = 0; fm < 4; ++fm)
        acc[fm][fn] = MFMA16(a_h[fm], b_h, acc[fm][fn]);
    }
    __syncthreads();
  }
  #undef ISSUE_OUT

  #pragma unroll
  for (int fm = 0; fm < 4; ++fm){
    #pragma unroll
    for (int fn = 0; fn < 2; ++fn){
      const int col = n0 + 32*wc + 16*fn + c;
      const float bb = bias[col];
      const int row0 = m0 + 64*wr + 16*fm + 4*g;
      #pragma unroll
      for (int r = 0; r < 4; ++r)
        outf[(size_t)(row0 + r)*DM + col] = acc[fm][fn][r] + bb;
    }
  }
}

// ---- Stats pass: QBLK=128 (512 thr, 8 waves), KVBLK=64, 1-term QK (Qh),
// plain-bf16 Q/K, prefetch. Atomic partial sums only (no election).
__global__ __launch_bounds__(512) void attn_stats_mfma(
    const ush* __restrict__ Qb, const ush* __restrict__ Kb,
    float* __restrict__ stats)
{
  __shared__ ush Khs[64*64];
  __shared__ float red[8][3];
  const int tid = threadIdx.x, lane = tid & 63, w = tid >> 6;   // w 0..7
  const int c = lane & 15, g = lane >> 4;
  const int fid = blockIdx.x;
  const int glob = (fid & 7)*64 + (fid >> 3);     // 512 blocks, XCD-chunked
  const int bh = glob >> 3, q0 = (glob & 7)*128;

  bf8_t qh[2];
  {
    const ush* qp = Qb + ((size_t)bh*SS + q0 + 16*w + c)*DKH + 8*g;
    qh[0] = *(const bf8_t*)(qp);
    qh[1] = *(const bf8_t*)(qp + 32);
  }

  float ssum = 0.f, rmax = -1e30f, lsum = 0.f, l2sum = 0.f;
  const int rr0 = tid >> 3, ci = tid & 7;         // 64 rows x 8 chunks

  uint4 k0;
  #define ISSUE_ST(KC) do{ \
    k0 = *(const uint4*)(Kb + ((size_t)bh*SS + (KC)*64 + rr0)*DKH + ci*8); \
  }while(0)

  ISSUE_ST(0);
  for (int kc = 0; kc < 16; ++kc){
    *(uint4*)&Khs[swz8(rr0, ci)] = k0;
    __syncthreads();
    if (kc < 15) ISSUE_ST(kc + 1);

    f32x4 sa[4];
    #pragma unroll
    for (int fn = 0; fn < 4; ++fn) sa[fn] = (f32x4){0.f,0.f,0.f,0.f};
    __builtin_amdgcn_s_setprio(1);
    #pragma unroll
    for (int fn = 0; fn < 4; ++fn){
      #pragma unroll
      for (int ds = 0; ds < 2; ++ds){
        bf8_t ah = *(const bf8_t*)&Khs[swz8(16*fn + c, g + 4*ds)];
        sa[fn] = MFMA16(ah, qh[ds], sa[fn]);      // 1-term: Kh . Qh
      }
    }
    __builtin_amdgcn_s_setprio(0);
    #pragma unroll
    for (int fn = 0; fn < 4; ++fn){
      #pragma unroll
      for (int r = 0; r < 4; ++r){
        float s = sa[fn][r] * 0.125f;
        ssum += s;
        rmax = fmaxf(rmax, s);
        float e = exp2f(s * 0.7213475204f);       // exp(s/2); |s|<50 fp32-safe
        lsum += e;
        l2sum = fmaf(e, e, l2sum);
      }
    }
    __syncthreads();
  }
  #undef ISSUE_ST

  rmax  = fmaxf(rmax, __shfl_xor(rmax, 16, 64));
  rmax  = fmaxf(rmax, __shfl_xor(rmax, 32, 64));
  lsum  += __shfl_xor(lsum, 16, 64);   lsum  += __shfl_xor(lsum, 32, 64);
  l2sum += __shfl_xor(l2sum, 16, 64);  l2sum += __shfl_xor(l2sum, 32, 64);
  float varc = (l2sum/(lsum*lsum) - (1.0f/1024.f)) * (1.0f/1023.f);
  float a0 = ssum, a1 = rmax * 0.25f, a2 = varc * 0.25f;
  #pragma unroll
  for (int off = 1; off < 64; off <<= 1){
    a0 += __shfl_xor(a0, off, 64);
    a1 += __shfl_xor(a1, off, 64);
    a2 += __shfl_xor(a2, off, 64);
  }
  if (lane == 0){ red[w][0] = a0; red[w][1] = a1; red[w][2] = a2; }
  __syncthreads();
  if (tid == 0){
    float r0 = 0.f, r1 = 0.f, r2 = 0.f;
    #pragma unroll
    for (int i = 0; i < 8; ++i){ r0 += red[i][0]; r1 += red[i][1]; r2 += red[i][2]; }
    atomicAdd(&stats[bh*4+0], r0);
    atomicAdd(&stats[bh*4+1], r1);
    atomicAdd(&stats[bh*4+2], r2);
  }
}

// ---- Flash pass: QBLK=128 (512 thr), KVBLK=64 (16 iters), swapped QK^T
// 1-term (Kh . Qh), plain-bf16 Q/K, exp2, defer-max, swizzled LDS, prefetch.
// LDS = 32 KB. Time-MLP in prologue, lane-parallel + LDS broadcast.
__global__ __launch_bounds__(512) void attn_flash_mfma(
    const ush* __restrict__ Qb, const ush* __restrict__ Kb,
    const ush* __restrict__ Vt, const float* __restrict__ stats,
    const float* __restrict__ Wt1, const float* __restrict__ bt1,
    const float* __restrict__ Wt2, const float* __restrict__ bt2,
    ush* __restrict__ aout)
{
  __shared__ ush Khs[64*64], Vts[64*64], Ps[128*64];
  __shared__ float tshare;
  const int tid = threadIdx.x, lane = tid & 63, w = tid >> 6;   // w 0..7
  const int c = lane & 15, g = lane >> 4;
  const int fid = blockIdx.x;
  const int glob = (fid & 7)*64 + (fid >> 3);     // 512 blocks, XCD-chunked
  const int bh = glob >> 3, q0 = (glob & 7)*128;

  // ---- lane-parallel time-MLP: lane j of wave 0 computes hidden unit j
  if (tid < 16){
    float mean = fminf(fmaxf(stats[bh*4+0] * (1.f/(1024.f*1024.f)), -10.f), 10.f);
    float mx   = fminf(fmaxf(stats[bh*4+1] * (1.f/1024.f), -10.f), 10.f);
    float ent  = fminf(fmaxf(stats[bh*4+2] * (1.f/1024.f),   0.f),  1.f);
    float h = tanhf(mean*Wt1[tid] + mx*Wt1[16+tid] + ent*Wt1[32+tid] + bt1[tid])
              * Wt2[tid];
    h += __shfl_xor(h, 1, 64);
    h += __shfl_xor(h, 2, 64);
    h += __shfl_xor(h, 4, 64);
    h += __shfl_xor(h, 8, 64);
    if (tid == 0){
      float raw = h + bt2[0];
      float sig = 1.f / (1.f + expf(-raw));
      float t = 0.01f + sig * 1.99f;
      t = fminf(fminf(fmaxf(t, 0.01f), 2.0f), 0.85f);
      tshare = (0.5f / t) * 1.44269504f;          // exp2 domain
    }
  }

  bf8_t qh[2];
  {
    const ush* qp = Qb + ((size_t)bh*SS + q0 + 16*w + c)*DKH + 8*g;
    qh[0] = *(const bf8_t*)(qp);
    qh[1] = *(const bf8_t*)(qp + 32);
  }

  f32x4 o[4];
  #pragma unroll
  for (int i = 0; i < 4; ++i) o[i] = (f32x4){0.f,0.f,0.f,0.f};
  float m = -INFINITY, lpart = 0.f;

  const int rr0 = tid >> 3, ci = tid & 7;         // 64 rows x 8 chunks

  uint4 k0, vr0;
  #define ISSUE_FL(KC) do{ \
    k0  = *(const uint4*)(Kb + ((size_t)bh*SS + (KC)*64 + rr0)*DKH + ci*8); \
    vr0 = *(const uint4*)(Vt + ((size_t)bh*DKH + rr0)*SS + (KC)*64 + ci*8); \
  }while(0)

  ISSUE_FL(0);
  *(uint4*)&Khs[swz8(rr0, ci)] = k0;
  *(uint4*)&Vts[swz8(rr0, ci)] = vr0;
  __syncthreads();                                 // staging + tshare visible
  const float tsc2 = tshare;

  for (int kc = 0; kc < 16; ++kc){
    if (kc){
      *(uint4*)&Khs[swz8(rr0, ci)] = k0;
      *(uint4*)&Vts[swz8(rr0, ci)] = vr0;
      __syncthreads();
    }
    if (kc < 15) ISSUE_FL(kc + 1);

    f32x4 sa[4];
    #pragma unroll
    for (int fn = 0; fn < 4; ++fn) sa[fn] = (f32x4){0.f,0.f,0.f,0.f};
    __builtin_amdgcn_s_setprio(1);
    #pragma unroll
    for (int fn = 0; fn < 4; ++fn){
      #pragma unroll
      for (int ds = 0; ds < 2; ++ds){
        bf8_t ah = *(const bf8_t*)&Khs[swz8(16*fn + c, g + 4*ds)];
        sa[fn] = MFMA16(ah, qh[ds], sa[fn]);   // 1-term: Kh . Qh
      }
    }
    __builtin_amdgcn_s_setprio(0);

    // lane-local max over own 16 kv; shuffles only in the rare rescale path
    float pmaxr = -1e30f;
    #pragma unroll
    for (int fn = 0; fn < 4; ++fn)
      #pragma unroll
      for (int r = 0; r < 4; ++r) pmaxr = fmaxf(pmaxr, sa[fn][r]);

    if (!__all(pmaxr * tsc2 <= m + 30.f)){     // fires ~once (kc=0)
      pmaxr = fmaxf(pmaxr, __shfl_xor(pmaxr, 16, 64));
      pmaxr = fmaxf(pmaxr, __shfl_xor(pmaxr, 32, 64));
      float pmax = pmaxr * tsc2;
      float mn = fmaxf(m, pmax);
      float sc = exp2f(m - mn);
      m = mn;
      lpart *= sc;
      #pragma unroll
      for (int r = 0; r < 4; ++r){
        float so = __shfl(sc, 4*g + r, 16);    // sc of q-row 4g+r (c'=4g+r)
        #pragma unroll
        for (int fn = 0; fn < 4; ++fn) o[fn][r] *= so;
      }
    }

    const float mneg = -m;
    #pragma unroll
    for (int fn = 0; fn < 4; ++fn){
      float e0 = exp2f(fmaf(sa[fn][0], tsc2, mneg));
      float e1 = exp2f(fmaf(sa[fn][1], tsc2, mneg));
      float e2 = exp2f(fmaf(sa[fn][2], tsc2, mneg));
      float e3 = exp2f(fmaf(sa[fn][3], tsc2, mneg));
      lpart += (e0 + e1) + (e2 + e3);
      uint2 pk;
      pk.x = pk2(e0, e1);
      pk.y = pk2(e2, e3);
      const int q4 = 4*fn + g;
      const int addr = (16*w + c)*64 + ((((q4 >> 1) ^ (c & 7)) << 3)) + (q4 & 1)*4;
      *(uint2*)&Ps[addr] = pk;
    }

    __builtin_amdgcn_s_setprio(1);
    #pragma unroll
    for (int kvs = 0; kvs < 2; ++kvs){
      bf8_t pa = *(const bf8_t*)&Ps[swz8(16*w + c, g + 4*kvs)];
      #pragma unroll
      for (int fn = 0; fn < 4; ++fn){
        bf8_t vb = *(const bf8_t*)&Vts[swz8(16*fn + c, g + 4*kvs)];
        o[fn] = MFMA16(pa, vb, o[fn]);
      }
    }
    __builtin_amdgcn_s_setprio(0);
    __syncthreads();
  }
  #undef ISSUE_FL

  lpart += __shfl_xor(lpart, 16, 64);
  lpart += __shfl_xor(lpart, 32, 64);
  const int b = bh >> 4, hd = bh & 15;
  #pragma unroll
  for (int r = 0; r < 4; ++r){
    float linv = 1.f / __shfl(lpart, 4*g + r, 16);   // l of q-row 4g+r
    const int q = q0 + 16*w + 4*g + r;
    #pragma unroll
    for (int fn = 0; fn < 4; ++fn)
      aout[((size_t)(b*SS + q))*DM + hd*DKH + 16*fn + c] = f2bf(o[fn][r] * linv);
  }
}

extern "C" void kernel_launch(void* const* d_in, const int* in_sizes, int n_in,
                              void* d_out, int out_size, void* d_ws, size_t ws_size,
                              hipStream_t stream)
{
  const float* query = (const float*)d_in[0];
  const float* key   = (const float*)d_in[1];
  const float* value = (const float*)d_in[2];
  const float* Wq = (const float*)d_in[3];
  const float* bq = (const float*)d_in[4];
  const float* Wk = (const float*)d_in[5];
  const float* bk = (const float*)d_in[6];
  const float* Wv = (const float*)d_in[7];
  const float* bv = (const float*)d_in[8];
  const float* Wo = (const float*)d_in[9];
  const float* bo = (const float*)d_in[10];
  const float* Wt1 = (const float*)d_in[11];
  const float* bt1 = (const float*)d_in[12];
  const float* Wt2 = (const float*)d_in[13];
  const float* bt2 = (const float*)d_in[14];

  const size_t E = (size_t)NB*SS*DM;       // 4,194,304
  const size_t WE = (size_t)DM*DM;

  ush* Qbb = (ush*)d_ws;                   // E ush (plain bf16)
  ush* Kbb = Qbb + E;                      // E ush
  ush* Vtb = Kbb + E;                      // E ush (b*16+h, dk, s)
  ush* Aob = Vtb + E;                      // E ush
  ush* Wqh = Aob + E;
  ush* Wkh = Wqh + WE;
  ush* Wvh = Wkh + WE;
  ush* Woh = Wvh + WE;
  float* stats = (float*)(Woh + WE);       // 256 floats

  hipMemsetAsync(stats, 0, 4*NBH*sizeof(float), stream);

  dim3 wb(32, 8), wg(32, 32, 4);
  wconv4<<<wg, wb, 0, stream>>>(Wq, Wk, Wv, Wo, Wqh, Wkh, Wvh, Woh);

  proj_qkv<<<768, 256, 0, stream>>>(query, key, value,
      Wqh, Wkh, Wvh, bq, bk, bv, Qbb, Kbb, Vtb);

  attn_stats_mfma<<<512, 512, 0, stream>>>(Qbb, Kbb, stats);
  attn_flash_mfma<<<512, 512, 0, stream>>>(Qbb, Kbb, Vtb, stats,
      Wt1, bt1, Wt2, bt2, Aob);

  gemm_out<<<512, 256, 0, stream>>>(Aob, Woh, bo, (float*)d_out);
}

// Round 22
// 144.656 us; speedup vs baseline: 1.1147x; 1.1147x over previous
//
#include <hip/hip_runtime.h>
#include <hip/hip_bf16.h>
#include <math.h>

#define SS   1024
#define DM   1024
#define NH   16
#define DKH  64
#define NB   4
#define NBH  64

typedef unsigned short ush;
typedef unsigned int uint32;
typedef __attribute__((ext_vector_type(8))) short bf8_t;   // 8 bf16 = 4 VGPR
typedef __attribute__((ext_vector_type(4))) float f32x4;
#define MFMA16(a,b,c) __builtin_amdgcn_mfma_f32_16x16x32_bf16((a),(b),(c),0,0,0)

__device__ __forceinline__ ush f2bf(float x){ return __bfloat16_as_ushort(__float2bfloat16(x)); }
__device__ __forceinline__ uint32 pk2(float a, float b){
  return (uint32)f2bf(a) | ((uint32)f2bf(b) << 16);
}
// [rows][64]-ush tile, XOR swizzle on 16B chunks
__device__ __forceinline__ int swz8(int row, int chunk){
  return row*64 + (((chunk) ^ (row & 7)) << 3);
}

// ---- x fp32 -> bf16 (hi only)
__global__ __launch_bounds__(256) void xconv(
    const float* __restrict__ q, const float* __restrict__ k, const float* __restrict__ v,
    ush* __restrict__ xq, ush* __restrict__ xk, ush* __restrict__ xv)
{
  const float* src = (blockIdx.y==0)?q:(blockIdx.y==1)?k:v;
  ush* dst = (blockIdx.y==0)?xq:(blockIdx.y==1)?xk:xv;
  const size_t i = ((size_t)blockIdx.x*256 + threadIdx.x)*8;
  float4 a = *(const float4*)&src[i];
  float4 b = *(const float4*)&src[i+4];
  uint4 o;
  o.x = pk2(a.x, a.y); o.y = pk2(a.z, a.w);
  o.z = pk2(b.x, b.y); o.w = pk2(b.z, b.w);
  *(uint4*)&dst[i] = o;
}

// ---- weight convert: W (K x N) fp32 -> Wt (N x K) bf16 hi only
__global__ void wconv4(const float* __restrict__ W0, const float* __restrict__ W1,
                       const float* __restrict__ W2, const float* __restrict__ W3,
                       ush* __restrict__ H0, ush* __restrict__ H1,
                       ush* __restrict__ H2, ush* __restrict__ H3)
{
  __shared__ float T[32][33];
  const int tx = threadIdx.x, ty = threadIdx.y;    // (32,8)
  const int z = blockIdx.z;
  const float* W = (z==0)?W0:(z==1)?W1:(z==2)?W2:W3;
  ush* H = (z==0)?H0:(z==1)?H1:(z==2)?H2:H3;
  const int k0 = blockIdx.y*32, n0 = blockIdx.x*32;
  #pragma unroll
  for (int i = 0; i < 4; ++i){
    int r = ty + 8*i;
    T[r][tx] = W[(size_t)(k0 + r)*DM + n0 + tx];
  }
  __syncthreads();
  #pragma unroll
  for (int i = 0; i < 4; ++i){
    int r = ty + 8*i;              // n-local
    H[(size_t)(n0 + r)*DM + k0 + tx] = f2bf(T[tx][r]);
  }
}

// ---- fused Q/K/V projection: BK=32, 1-term (W hi), double-buffered LDS via
// global_load_lds width-16 with pre-swizzled per-lane SOURCE addresses.
// Q/K out plain bf16 (b*16+h, s, dk); V out bf16 transposed (b*16+h, dk, s).
__global__ __launch_bounds__(256) void proj_qkv(
    const ush* __restrict__ xq, const ush* __restrict__ xk, const ush* __restrict__ xv,
    const ush* __restrict__ Wqh, const ush* __restrict__ Wkh, const ush* __restrict__ Wvh,
    const float* __restrict__ bq, const float* __restrict__ bk,
    const float* __restrict__ bv,
    ush* __restrict__ Qb, ush* __restrict__ Kb, ush* __restrict__ Vt)
{
  // staging: 2 buffers x (As 4096 | Bhs 4096) = 32 KB; V-epilogue 4*4224 ush
  __shared__ ush SMEM[16896];

  const int fid = blockIdx.x;
  const int glob = (fid & 7)*96 + (fid >> 3);  // XCD-contiguous chunks of 96
  const int z = glob >> 8, rem = glob & 255;
  const int m0 = (rem >> 3) * 128, n0 = (rem & 7) * 128;

  const ush* A  = (z==0) ? xq  : (z==1) ? xk  : xv;
  const ush* Bh = (z==0) ? Wqh : (z==1) ? Wkh : Wvh;

  const int tid = threadIdx.x;
  const int lane = tid & 63, w = tid >> 6;
  const int c = lane & 15, g = lane >> 4;
  const int wr = w >> 1, wc = w & 1;

  f32x4 acc[4][4];
  #pragma unroll
  for (int i = 0; i < 4; ++i)
    #pragma unroll
    for (int j = 0; j < 4; ++j) acc[i][j] = (f32x4){0.f,0.f,0.f,0.f};

  const int prow0 = w*16 + (lane >> 3), prow1 = prow0 + 8;
  const int jj = lane & 7;
  const int sg0 = jj ^ (prow0 & 7), sg1 = jj ^ (prow1 & 7);
  const size_t aoff0 = (size_t)(2*prow0 + (sg0 >> 2))*DM + (sg0 & 3)*8;
  const size_t aoff1 = (size_t)(2*prow1 + (sg1 >> 2))*DM + (sg1 & 3)*8;
  const ush* Aab = A  + (size_t)m0*DM;
  const ush* Bhb = Bh + (size_t)n0*DM;
  const int lb0 = w*1024, lb1 = w*1024 + 512;   // wave-uniform LDS bases (ush)

#define GLL(GP, LIDX) __builtin_amdgcn_global_load_lds( \
    (const __attribute__((address_space(1))) unsigned int*)(GP), \
    (__attribute__((address_space(3))) unsigned int*)(&SMEM[LIDX]), 16, 0, 0)

#define ISSUE_PROJ(BUFO, KT) do{ \
    GLL(Aab + aoff0 + (KT), (BUFO) + lb0); \
    GLL(Aab + aoff1 + (KT), (BUFO) + lb1); \
    GLL(Bhb + aoff0 + (KT), (BUFO) + 4096 + lb0); \
    GLL(Bhb + aoff1 + (KT), (BUFO) + 4096 + lb1); \
  }while(0)

  const int csw = (((4*(c & 1) + g) ^ ((c >> 1) & 7)) << 3);

  ISSUE_PROJ(0, 0);
  int cur = 0;
  for (int kt = 0; kt < DM; kt += 32){
    __syncthreads();                       // drains vmcnt -> buf[cur] ready
    if (kt + 32 < DM) ISSUE_PROJ((cur ^ 1)*8192, kt + 32);

    const ush* As  = SMEM + cur*8192;
    const ush* Bhs = As + 4096;

    bf8_t a_h[4];
    #pragma unroll
    for (int fm = 0; fm < 4; ++fm)
      a_h[fm] = *(const bf8_t*)&As[(32*wr + 8*fm + (c>>1))*64 + csw];
    __builtin_amdgcn_s_setprio(1);
    #pragma unroll
    for (int fn = 0; fn < 4; ++fn){
      bf8_t b_h = *(const bf8_t*)&Bhs[(32*wc + 8*fn + (c>>1))*64 + csw];
      #pragma unroll
      for (int fm = 0; fm < 4; ++fm)
        acc[fm][fn] = MFMA16(a_h[fm], b_h, acc[fm][fn]);
    }
    __builtin_amdgcn_s_setprio(0);
    cur ^= 1;
  }
#undef ISSUE_PROJ
#undef GLL

  if (z < 2){
    ush* O = (z==0) ? Qb : Kb;
    const float* bias = (z==0) ? bq : bk;
    #pragma unroll
    for (int fm = 0; fm < 4; ++fm){
      #pragma unroll
      for (int fn = 0; fn < 4; ++fn){
        const int col = n0 + 64*wc + 16*fn + c;
        const float bb = bias[col];
        const int row0 = m0 + 64*wr + 16*fm + 4*g;
        const int hd = col >> 6, d = col & 63;
        #pragma unroll
        for (int r = 0; r < 4; ++r){
          const int row = row0 + r;
          const int b = row >> 10, s = row & 1023;
          O[((size_t)(b*NH + hd)*SS + s)*DKH + d] = f2bf(acc[fm][fn][r] + bb);
        }
      }
    }
  } else {
    // V: transpose wave's 64(s) x 64(d) sub-tile through LDS -> coalesced (d,s)
    __syncthreads();                      // all waves done reading staging LDS
    ush* Vep = SMEM + w*4224;             // 64 rows(d) x 66 cols(s)
    #pragma unroll
    for (int fm = 0; fm < 4; ++fm){
      #pragma unroll
      for (int fn = 0; fn < 4; ++fn){
        const float bb = bv[n0 + 64*wc + 16*fn + c];
        #pragma unroll
        for (int r = 0; r < 4; ++r)
          Vep[(16*fn + c)*66 + 16*fm + 4*g + r] = f2bf(acc[fm][fn][r] + bb);
      }
    }
    const int b = m0 >> 10;
    const int s0 = (m0 & 1023) + 64*wr;
    const int hd = (n0 >> 6) + wc;
    const size_t vbase = ((size_t)(b*NH + hd))*DKH*SS;
    #pragma unroll
    for (int it = 0; it < 8; ++it){
      const int dr = 8*it + (lane >> 3);
      const int sc = (lane & 7)*8;
      uint4 vv = *(const uint4*)&Vep[dr*66 + sc];
      *(uint4*)&Vt[vbase + (size_t)dr*SS + s0 + sc] = vv;
    }
  }
}

// ---- output projection: C = A(bf16) @ Wo^T + bo, 128x64 tile, paired-row LDS
__global__ __launch_bounds__(256) void gemm_out(
    const ush* __restrict__ Abf, const ush* __restrict__ Bth,
    const float* __restrict__ bias, float* __restrict__ outf)
{
  __shared__ ush As[4096], Bs[2048];

  const int fid = blockIdx.x;
  const int glob = (fid & 7)*64 + (fid >> 3);
  const int m0 = (glob >> 4)*128, n0 = (glob & 15)*64;

  const int tid = threadIdx.x;
  const int lane = tid & 63, w = tid >> 6;
  const int c = lane & 15, g = lane >> 4;
  const int wr = w >> 1, wc = w & 1;

  f32x4 acc[4][2];
  #pragma unroll
  for (int i = 0; i < 4; ++i){ acc[i][0] = (f32x4){0,0,0,0}; acc[i][1] = (f32x4){0,0,0,0}; }

  const int prow = tid >> 3, ci = tid & 7;
  const int lr   = 2*prow + (ci >> 2);
  const int koff = (ci & 3) << 3;
  const int ws0  = prow*64 + ((ci ^ (prow & 7)) << 3);
  const int ws1  = ws0 + 32*64;
  const int csw  = (((4*(c & 1) + g) ^ ((c >> 1) & 7)) << 3);

  uint4 ar0, ar1, brr;
  #define ISSUE_OUT(KT) do{ \
    ar0 = *(const uint4*)(Abf + (size_t)(m0 + lr)*DM + (KT) + koff); \
    ar1 = *(const uint4*)(Abf + (size_t)(m0 + lr + 64)*DM + (KT) + koff); \
    brr = *(const uint4*)(Bth + (size_t)(n0 + lr)*DM + (KT) + koff); \
  }while(0)

  ISSUE_OUT(0);
  for (int kt = 0; kt < DM; kt += 32){
    *(uint4*)&As[ws0] = ar0;
    *(uint4*)&As[ws1] = ar1;
    if (lr < 64) *(uint4*)&Bs[ws0] = brr;
    __syncthreads();
    if (kt + 32 < DM) ISSUE_OUT(kt + 32);

    bf8_t a_h[4];
    #pragma unroll
    for (int fm = 0; fm < 4; ++fm)
      a_h[fm] = *(const bf8_t*)&As[(32*wr + 8*fm + (c>>1))*64 + csw];
    #pragma unroll
    for (int fn = 0; fn < 2; ++fn){
      bf8_t b_h = *(const bf8_t*)&Bs[(16*wc + 8*fn + (c>>1))*64 + csw];
      #pragma unroll
      for (int fm = 0; fm < 4; ++fm)
        acc[fm][fn] = MFMA16(a_h[fm], b_h, acc[fm][fn]);
    }
    __syncthreads();
  }
  #undef ISSUE_OUT

  #pragma unroll
  for (int fm = 0; fm < 4; ++fm){
    #pragma unroll
    for (int fn = 0; fn < 2; ++fn){
      const int col = n0 + 32*wc + 16*fn + c;
      const float bb = bias[col];
      const int row0 = m0 + 64*wr + 16*fm + 4*g;
      #pragma unroll
      for (int r = 0; r < 4; ++r)
        outf[(size_t)(row0 + r)*DM + col] = acc[fm][fn][r] + bb;
    }
  }
}

// ---- Stats pass: QBLK=128 (512 thr, 8 waves), KVBLK=64, 1-term QK (Qh),
// plain-bf16 Q/K, prefetch. Atomic partial sums only (no election).
__global__ __launch_bounds__(512) void attn_stats_mfma(
    const ush* __restrict__ Qb, const ush* __restrict__ Kb,
    float* __restrict__ stats)
{
  __shared__ ush Khs[64*64];
  __shared__ float red[8][3];
  const int tid = threadIdx.x, lane = tid & 63, w = tid >> 6;   // w 0..7
  const int c = lane & 15, g = lane >> 4;
  const int fid = blockIdx.x;
  const int glob = (fid & 7)*64 + (fid >> 3);     // 512 blocks, XCD-chunked
  const int bh = glob >> 3, q0 = (glob & 7)*128;

  bf8_t qh[2];
  {
    const ush* qp = Qb + ((size_t)bh*SS + q0 + 16*w + c)*DKH + 8*g;
    qh[0] = *(const bf8_t*)(qp);
    qh[1] = *(const bf8_t*)(qp + 32);
  }

  float ssum = 0.f, rmax = -1e30f, lsum = 0.f, l2sum = 0.f;
  const int rr0 = tid >> 3, ci = tid & 7;         // 64 rows x 8 chunks

  uint4 k0;
  #define ISSUE_ST(KC) do{ \
    k0 = *(const uint4*)(Kb + ((size_t)bh*SS + (KC)*64 + rr0)*DKH + ci*8); \
  }while(0)

  ISSUE_ST(0);
  for (int kc = 0; kc < 16; ++kc){
    *(uint4*)&Khs[swz8(rr0, ci)] = k0;
    __syncthreads();
    if (kc < 15) ISSUE_ST(kc + 1);

    f32x4 sa[4];
    #pragma unroll
    for (int fn = 0; fn < 4; ++fn) sa[fn] = (f32x4){0.f,0.f,0.f,0.f};
    __builtin_amdgcn_s_setprio(1);
    #pragma unroll
    for (int fn = 0; fn < 4; ++fn){
      #pragma unroll
      for (int ds = 0; ds < 2; ++ds){
        bf8_t ah = *(const bf8_t*)&Khs[swz8(16*fn + c, g + 4*ds)];
        sa[fn] = MFMA16(ah, qh[ds], sa[fn]);      // 1-term: Kh . Qh
      }
    }
    __builtin_amdgcn_s_setprio(0);
    #pragma unroll
    for (int fn = 0; fn < 4; ++fn){
      #pragma unroll
      for (int r = 0; r < 4; ++r){
        float s = sa[fn][r] * 0.125f;
        ssum += s;
        rmax = fmaxf(rmax, s);
        float e = exp2f(s * 0.7213475204f);       // exp(s/2); |s|<50 fp32-safe
        lsum += e;
        l2sum = fmaf(e, e, l2sum);
      }
    }
    __syncthreads();
  }
  #undef ISSUE_ST

  rmax  = fmaxf(rmax, __shfl_xor(rmax, 16, 64));
  rmax  = fmaxf(rmax, __shfl_xor(rmax, 32, 64));
  lsum  += __shfl_xor(lsum, 16, 64);   lsum  += __shfl_xor(lsum, 32, 64);
  l2sum += __shfl_xor(l2sum, 16, 64);  l2sum += __shfl_xor(l2sum, 32, 64);
  float varc = (l2sum/(lsum*lsum) - (1.0f/1024.f)) * (1.0f/1023.f);
  float a0 = ssum, a1 = rmax * 0.25f, a2 = varc * 0.25f;
  #pragma unroll
  for (int off = 1; off < 64; off <<= 1){
    a0 += __shfl_xor(a0, off, 64);
    a1 += __shfl_xor(a1, off, 64);
    a2 += __shfl_xor(a2, off, 64);
  }
  if (lane == 0){ red[w][0] = a0; red[w][1] = a1; red[w][2] = a2; }
  __syncthreads();
  if (tid == 0){
    float r0 = 0.f, r1 = 0.f, r2 = 0.f;
    #pragma unroll
    for (int i = 0; i < 8; ++i){ r0 += red[i][0]; r1 += red[i][1]; r2 += red[i][2]; }
    atomicAdd(&stats[bh*4+0], r0);
    atomicAdd(&stats[bh*4+1], r1);
    atomicAdd(&stats[bh*4+2], r2);
  }
}

// ---- Flash pass: QBLK=128 (512 thr), KVBLK=64 (16 iters), swapped QK^T
// 1-term (Kh . Qh), plain-bf16 Q/K, exp2, defer-max, swizzled LDS, prefetch.
// LDS = 32 KB. Time-MLP in prologue, lane-parallel + LDS broadcast.
__global__ __launch_bounds__(512) void attn_flash_mfma(
    const ush* __restrict__ Qb, const ush* __restrict__ Kb,
    const ush* __restrict__ Vt, const float* __restrict__ stats,
    const float* __restrict__ Wt1, const float* __restrict__ bt1,
    const float* __restrict__ Wt2, const float* __restrict__ bt2,
    ush* __restrict__ aout)
{
  __shared__ ush Khs[64*64], Vts[64*64], Ps[128*64];
  __shared__ float tshare;
  const int tid = threadIdx.x, lane = tid & 63, w = tid >> 6;   // w 0..7
  const int c = lane & 15, g = lane >> 4;
  const int fid = blockIdx.x;
  const int glob = (fid & 7)*64 + (fid >> 3);     // 512 blocks, XCD-chunked
  const int bh = glob >> 3, q0 = (glob & 7)*128;

  // ---- lane-parallel time-MLP: lane j of wave 0 computes hidden unit j
  if (tid < 16){
    float mean = fminf(fmaxf(stats[bh*4+0] * (1.f/(1024.f*1024.f)), -10.f), 10.f);
    float mx   = fminf(fmaxf(stats[bh*4+1] * (1.f/1024.f), -10.f), 10.f);
    float ent  = fminf(fmaxf(stats[bh*4+2] * (1.f/1024.f),   0.f),  1.f);
    float h = tanhf(mean*Wt1[tid] + mx*Wt1[16+tid] + ent*Wt1[32+tid] + bt1[tid])
              * Wt2[tid];
    h += __shfl_xor(h, 1, 64);
    h += __shfl_xor(h, 2, 64);
    h += __shfl_xor(h, 4, 64);
    h += __shfl_xor(h, 8, 64);
    if (tid == 0){
      float raw = h + bt2[0];
      float sig = 1.f / (1.f + expf(-raw));
      float t = 0.01f + sig * 1.99f;
      t = fminf(fminf(fmaxf(t, 0.01f), 2.0f), 0.85f);
      tshare = (0.5f / t) * 1.44269504f;          // exp2 domain
    }
  }

  bf8_t qh[2];
  {
    const ush* qp = Qb + ((size_t)bh*SS + q0 + 16*w + c)*DKH + 8*g;
    qh[0] = *(const bf8_t*)(qp);
    qh[1] = *(const bf8_t*)(qp + 32);
  }

  f32x4 o[4];
  #pragma unroll
  for (int i = 0; i < 4; ++i) o[i] = (f32x4){0.f,0.f,0.f,0.f};
  float m = -INFINITY, lpart = 0.f;

  const int rr0 = tid >> 3, ci = tid & 7;         // 64 rows x 8 chunks

  uint4 k0, vr0;
  #define ISSUE_FL(KC) do{ \
    k0  = *(const uint4*)(Kb + ((size_t)bh*SS + (KC)*64 + rr0)*DKH + ci*8); \
    vr0 = *(const uint4*)(Vt + ((size_t)bh*DKH + rr0)*SS + (KC)*64 + ci*8); \
  }while(0)

  ISSUE_FL(0);
  *(uint4*)&Khs[swz8(rr0, ci)] = k0;
  *(uint4*)&Vts[swz8(rr0, ci)] = vr0;
  __syncthreads();                                 // staging + tshare visible
  const float tsc2 = tshare;

  for (int kc = 0; kc < 16; ++kc){
    if (kc){
      *(uint4*)&Khs[swz8(rr0, ci)] = k0;
      *(uint4*)&Vts[swz8(rr0, ci)] = vr0;
      __syncthreads();
    }
    if (kc < 15) ISSUE_FL(kc + 1);

    f32x4 sa[4];
    #pragma unroll
    for (int fn = 0; fn < 4; ++fn) sa[fn] = (f32x4){0.f,0.f,0.f,0.f};
    __builtin_amdgcn_s_setprio(1);
    #pragma unroll
    for (int fn = 0; fn < 4; ++fn){
      #pragma unroll
      for (int ds = 0; ds < 2; ++ds){
        bf8_t ah = *(const bf8_t*)&Khs[swz8(16*fn + c, g + 4*ds)];
        sa[fn] = MFMA16(ah, qh[ds], sa[fn]);   // 1-term: Kh . Qh
      }
    }
    __builtin_amdgcn_s_setprio(0);

    // lane-local max over own 16 kv; shuffles only in the rare rescale path
    float pmaxr = -1e30f;
    #pragma unroll
    for (int fn = 0; fn < 4; ++fn)
      #pragma unroll
      for (int r = 0; r < 4; ++r) pmaxr = fmaxf(pmaxr, sa[fn][r]);

    if (!__all(pmaxr * tsc2 <= m + 30.f)){     // fires ~once (kc=0)
      pmaxr = fmaxf(pmaxr, __shfl_xor(pmaxr, 16, 64));
      pmaxr = fmaxf(pmaxr, __shfl_xor(pmaxr, 32, 64));
      float pmax = pmaxr * tsc2;
      float mn = fmaxf(m, pmax);
      float sc = exp2f(m - mn);
      m = mn;
      lpart *= sc;
      #pragma unroll
      for (int r = 0; r < 4; ++r){
        float so = __shfl(sc, 4*g + r, 16);    // sc of q-row 4g+r (c'=4g+r)
        #pragma unroll
        for (int fn = 0; fn < 4; ++fn) o[fn][r] *= so;
      }
    }

    const float mneg = -m;
    #pragma unroll
    for (int fn = 0; fn < 4; ++fn){
      float e0 = exp2f(fmaf(sa[fn][0], tsc2, mneg));
      float e1 = exp2f(fmaf(sa[fn][1], tsc2, mneg));
      float e2 = exp2f(fmaf(sa[fn][2], tsc2, mneg));
      float e3 = exp2f(fmaf(sa[fn][3], tsc2, mneg));
      lpart += (e0 + e1) + (e2 + e3);
      uint2 pk;
      pk.x = pk2(e0, e1);
      pk.y = pk2(e2, e3);
      const int q4 = 4*fn + g;
      const int addr = (16*w + c)*64 + ((((q4 >> 1) ^ (c & 7)) << 3)) + (q4 & 1)*4;
      *(uint2*)&Ps[addr] = pk;
    }

    __builtin_amdgcn_s_setprio(1);
    #pragma unroll
    for (int kvs = 0; kvs < 2; ++kvs){
      bf8_t pa = *(const bf8_t*)&Ps[swz8(16*w + c, g + 4*kvs)];
      #pragma unroll
      for (int fn = 0; fn < 4; ++fn){
        bf8_t vb = *(const bf8_t*)&Vts[swz8(16*fn + c, g + 4*kvs)];
        o[fn] = MFMA16(pa, vb, o[fn]);
      }
    }
    __builtin_amdgcn_s_setprio(0);
    __syncthreads();
  }
  #undef ISSUE_FL

  lpart += __shfl_xor(lpart, 16, 64);
  lpart += __shfl_xor(lpart, 32, 64);
  const int b = bh >> 4, hd = bh & 15;
  #pragma unroll
  for (int r = 0; r < 4; ++r){
    float linv = 1.f / __shfl(lpart, 4*g + r, 16);   // l of q-row 4g+r
    const int q = q0 + 16*w + 4*g + r;
    #pragma unroll
    for (int fn = 0; fn < 4; ++fn)
      aout[((size_t)(b*SS + q))*DM + hd*DKH + 16*fn + c] = f2bf(o[fn][r] * linv);
  }
}

extern "C" void kernel_launch(void* const* d_in, const int* in_sizes, int n_in,
                              void* d_out, int out_size, void* d_ws, size_t ws_size,
                              hipStream_t stream)
{
  const float* query = (const float*)d_in[0];
  const float* key   = (const float*)d_in[1];
  const float* value = (const float*)d_in[2];
  const float* Wq = (const float*)d_in[3];
  const float* bq = (const float*)d_in[4];
  const float* Wk = (const float*)d_in[5];
  const float* bk = (const float*)d_in[6];
  const float* Wv = (const float*)d_in[7];
  const float* bv = (const float*)d_in[8];
  const float* Wo = (const float*)d_in[9];
  const float* bo = (const float*)d_in[10];
  const float* Wt1 = (const float*)d_in[11];
  const float* bt1 = (const float*)d_in[12];
  const float* Wt2 = (const float*)d_in[13];
  const float* bt2 = (const float*)d_in[14];

  const size_t E = (size_t)NB*SS*DM;       // 4,194,304
  const size_t WE = (size_t)DM*DM;

  ush* Qbb = (ush*)d_ws;                   // E ush (plain bf16)
  ush* Kbb = Qbb + E;                      // E ush
  ush* Vtb = Kbb + E;                      // E ush (b*16+h, dk, s)
  ush* Aob = Vtb + E;                      // E ush  -- also aliased as xqb
  ush* xqb = Aob;                          // alias: consumed before Aob written
  ush* xkb = Aob + E;
  ush* xvb = xkb + E;
  ush* Wqh = xvb + E;
  ush* Wkh = Wqh + WE;
  ush* Wvh = Wkh + WE;
  ush* Woh = Wvh + WE;
  float* stats = (float*)(Woh + WE);       // 256 floats

  hipMemsetAsync(stats, 0, 4*NBH*sizeof(float), stream);

  xconv<<<dim3(2048, 3), 256, 0, stream>>>(query, key, value, xqb, xkb, xvb);

  dim3 wb(32, 8), wg(32, 32, 4);
  wconv4<<<wg, wb, 0, stream>>>(Wq, Wk, Wv, Wo, Wqh, Wkh, Wvh, Woh);

  proj_qkv<<<768, 256, 0, stream>>>(xqb, xkb, xvb,
      Wqh, Wkh, Wvh, bq, bk, bv, Qbb, Kbb, Vtb);

  attn_stats_mfma<<<512, 512, 0, stream>>>(Qbb, Kbb, stats);
  attn_flash_mfma<<<512, 512, 0, stream>>>(Qbb, Kbb, Vtb, stats,
      Wt1, bt1, Wt2, bt2, Aob);

  gemm_out<<<512, 256, 0, stream>>>(Aob, Woh, bo, (float*)d_out);
}

// Round 23
// 138.836 us; speedup vs baseline: 1.1614x; 1.0419x over previous
//
#include <hip/hip_runtime.h>
#include <hip/hip_bf16.h>
#include <math.h>

#define SS   1024
#define DM   1024
#define NH   16
#define DKH  64
#define NB   4
#define NBH  64

typedef unsigned short ush;
typedef unsigned int uint32;
typedef __attribute__((ext_vector_type(8))) short bf8_t;   // 8 bf16 = 4 VGPR
typedef __attribute__((ext_vector_type(4))) float f32x4;
#define MFMA16(a,b,c) __builtin_amdgcn_mfma_f32_16x16x32_bf16((a),(b),(c),0,0,0)

__device__ __forceinline__ ush f2bf(float x){ return __bfloat16_as_ushort(__float2bfloat16(x)); }
__device__ __forceinline__ uint32 pk2(float a, float b){
  return (uint32)f2bf(a) | ((uint32)f2bf(b) << 16);
}
// [rows][64]-ush tile, XOR swizzle on 16B chunks
__device__ __forceinline__ int swz8(int row, int chunk){
  return row*64 + (((chunk) ^ (row & 7)) << 3);
}

// ---- x fp32 -> bf16 (hi only)
__global__ __launch_bounds__(256) void xconv(
    const float* __restrict__ q, const float* __restrict__ k, const float* __restrict__ v,
    ush* __restrict__ xq, ush* __restrict__ xk, ush* __restrict__ xv)
{
  const float* src = (blockIdx.y==0)?q:(blockIdx.y==1)?k:v;
  ush* dst = (blockIdx.y==0)?xq:(blockIdx.y==1)?xk:xv;
  const size_t i = ((size_t)blockIdx.x*256 + threadIdx.x)*8;
  float4 a = *(const float4*)&src[i];
  float4 b = *(const float4*)&src[i+4];
  uint4 o;
  o.x = pk2(a.x, a.y); o.y = pk2(a.z, a.w);
  o.z = pk2(b.x, b.y); o.w = pk2(b.z, b.w);
  *(uint4*)&dst[i] = o;
}

// ---- weight convert: W (K x N) fp32 -> Wt (N x K) bf16 hi only
__global__ void wconv4(const float* __restrict__ W0, const float* __restrict__ W1,
                       const float* __restrict__ W2, const float* __restrict__ W3,
                       ush* __restrict__ H0, ush* __restrict__ H1,
                       ush* __restrict__ H2, ush* __restrict__ H3)
{
  __shared__ float T[32][33];
  const int tx = threadIdx.x, ty = threadIdx.y;    // (32,8)
  const int z = blockIdx.z;
  const float* W = (z==0)?W0:(z==1)?W1:(z==2)?W2:W3;
  ush* H = (z==0)?H0:(z==1)?H1:(z==2)?H2:H3;
  const int k0 = blockIdx.y*32, n0 = blockIdx.x*32;
  #pragma unroll
  for (int i = 0; i < 4; ++i){
    int r = ty + 8*i;
    T[r][tx] = W[(size_t)(k0 + r)*DM + n0 + tx];
  }
  __syncthreads();
  #pragma unroll
  for (int i = 0; i < 4; ++i){
    int r = ty + 8*i;              // n-local
    H[(size_t)(n0 + r)*DM + k0 + tx] = f2bf(T[tx][r]);
  }
}

// ---- fused Q/K/V projection: BK=32, 1-term (W hi), double-buffered LDS via
// global_load_lds width-16 with pre-swizzled per-lane SOURCE addresses.
// Q/K out plain bf16 (b*16+h, s, dk); V out bf16 transposed (b*16+h, dk, s).
__global__ __launch_bounds__(256) void proj_qkv(
    const ush* __restrict__ xq, const ush* __restrict__ xk, const ush* __restrict__ xv,
    const ush* __restrict__ Wqh, const ush* __restrict__ Wkh, const ush* __restrict__ Wvh,
    const float* __restrict__ bq, const float* __restrict__ bk,
    const float* __restrict__ bv,
    ush* __restrict__ Qb, ush* __restrict__ Kb, ush* __restrict__ Vt)
{
  // staging: 2 buffers x (As 4096 | Bhs 4096) = 32 KB; V-epilogue 4*4224 ush
  __shared__ ush SMEM[16896];

  const int fid = blockIdx.x;
  const int glob = (fid & 7)*96 + (fid >> 3);  // XCD-contiguous chunks of 96
  const int z = glob >> 8, rem = glob & 255;
  const int m0 = (rem >> 3) * 128, n0 = (rem & 7) * 128;

  const ush* A  = (z==0) ? xq  : (z==1) ? xk  : xv;
  const ush* Bh = (z==0) ? Wqh : (z==1) ? Wkh : Wvh;

  const int tid = threadIdx.x;
  const int lane = tid & 63, w = tid >> 6;
  const int c = lane & 15, g = lane >> 4;
  const int wr = w >> 1, wc = w & 1;

  f32x4 acc[4][4];
  #pragma unroll
  for (int i = 0; i < 4; ++i)
    #pragma unroll
    for (int j = 0; j < 4; ++j) acc[i][j] = (f32x4){0.f,0.f,0.f,0.f};

  const int prow0 = w*16 + (lane >> 3), prow1 = prow0 + 8;
  const int jj = lane & 7;
  const int sg0 = jj ^ (prow0 & 7), sg1 = jj ^ (prow1 & 7);
  const size_t aoff0 = (size_t)(2*prow0 + (sg0 >> 2))*DM + (sg0 & 3)*8;
  const size_t aoff1 = (size_t)(2*prow1 + (sg1 >> 2))*DM + (sg1 & 3)*8;
  const ush* Aab = A  + (size_t)m0*DM;
  const ush* Bhb = Bh + (size_t)n0*DM;
  const int lb0 = w*1024, lb1 = w*1024 + 512;   // wave-uniform LDS bases (ush)

#define GLL(GP, LIDX) __builtin_amdgcn_global_load_lds( \
    (const __attribute__((address_space(1))) unsigned int*)(GP), \
    (__attribute__((address_space(3))) unsigned int*)(&SMEM[LIDX]), 16, 0, 0)

#define ISSUE_PROJ(BUFO, KT) do{ \
    GLL(Aab + aoff0 + (KT), (BUFO) + lb0); \
    GLL(Aab + aoff1 + (KT), (BUFO) + lb1); \
    GLL(Bhb + aoff0 + (KT), (BUFO) + 4096 + lb0); \
    GLL(Bhb + aoff1 + (KT), (BUFO) + 4096 + lb1); \
  }while(0)

  const int csw = (((4*(c & 1) + g) ^ ((c >> 1) & 7)) << 3);

  ISSUE_PROJ(0, 0);
  int cur = 0;
  for (int kt = 0; kt < DM; kt += 32){
    __syncthreads();                       // drains vmcnt -> buf[cur] ready
    if (kt + 32 < DM) ISSUE_PROJ((cur ^ 1)*8192, kt + 32);

    const ush* As  = SMEM + cur*8192;
    const ush* Bhs = As + 4096;

    bf8_t a_h[4];
    #pragma unroll
    for (int fm = 0; fm < 4; ++fm)
      a_h[fm] = *(const bf8_t*)&As[(32*wr + 8*fm + (c>>1))*64 + csw];
    __builtin_amdgcn_s_setprio(1);
    #pragma unroll
    for (int fn = 0; fn < 4; ++fn){
      bf8_t b_h = *(const bf8_t*)&Bhs[(32*wc + 8*fn + (c>>1))*64 + csw];
      #pragma unroll
      for (int fm = 0; fm < 4; ++fm)
        acc[fm][fn] = MFMA16(a_h[fm], b_h, acc[fm][fn]);
    }
    __builtin_amdgcn_s_setprio(0);
    cur ^= 1;
  }
#undef ISSUE_PROJ
#undef GLL

  if (z < 2){
    ush* O = (z==0) ? Qb : Kb;
    const float* bias = (z==0) ? bq : bk;
    #pragma unroll
    for (int fm = 0; fm < 4; ++fm){
      #pragma unroll
      for (int fn = 0; fn < 4; ++fn){
        const int col = n0 + 64*wc + 16*fn + c;
        const float bb = bias[col];
        const int row0 = m0 + 64*wr + 16*fm + 4*g;
        const int hd = col >> 6, d = col & 63;
        #pragma unroll
        for (int r = 0; r < 4; ++r){
          const int row = row0 + r;
          const int b = row >> 10, s = row & 1023;
          O[((size_t)(b*NH + hd)*SS + s)*DKH + d] = f2bf(acc[fm][fn][r] + bb);
        }
      }
    }
  } else {
    // V: transpose wave's 64(s) x 64(d) sub-tile through LDS -> coalesced (d,s)
    __syncthreads();                      // all waves done reading staging LDS
    ush* Vep = SMEM + w*4224;             // 64 rows(d) x 66 cols(s)
    #pragma unroll
    for (int fm = 0; fm < 4; ++fm){
      #pragma unroll
      for (int fn = 0; fn < 4; ++fn){
        const float bb = bv[n0 + 64*wc + 16*fn + c];
        #pragma unroll
        for (int r = 0; r < 4; ++r)
          Vep[(16*fn + c)*66 + 16*fm + 4*g + r] = f2bf(acc[fm][fn][r] + bb);
      }
    }
    const int b = m0 >> 10;
    const int s0 = (m0 & 1023) + 64*wr;
    const int hd = (n0 >> 6) + wc;
    const size_t vbase = ((size_t)(b*NH + hd))*DKH*SS;
    #pragma unroll
    for (int it = 0; it < 8; ++it){
      const int dr = 8*it + (lane >> 3);
      const int sc = (lane & 7)*8;
      uint4 vv = *(const uint4*)&Vep[dr*66 + sc];
      *(uint4*)&Vt[vbase + (size_t)dr*SS + s0 + sc] = vv;
    }
  }
}

// ---- output projection: C = A(bf16) @ Wo^T + bo, 128x64 tile, paired-row LDS
__global__ __launch_bounds__(256) void gemm_out(
    const ush* __restrict__ Abf, const ush* __restrict__ Bth,
    const float* __restrict__ bias, float* __restrict__ outf)
{
  __shared__ ush As[4096], Bs[2048];

  const int fid = blockIdx.x;
  const int glob = (fid & 7)*64 + (fid >> 3);
  const int m0 = (glob >> 4)*128, n0 = (glob & 15)*64;

  const int tid = threadIdx.x;
  const int lane = tid & 63, w = tid >> 6;
  const int c = lane & 15, g = lane >> 4;
  const int wr = w >> 1, wc = w & 1;

  f32x4 acc[4][2];
  #pragma unroll
  for (int i = 0; i < 4; ++i){ acc[i][0] = (f32x4){0,0,0,0}; acc[i][1] = (f32x4){0,0,0,0}; }

  const int prow = tid >> 3, ci = tid & 7;
  const int lr   = 2*prow + (ci >> 2);
  const int koff = (ci & 3) << 3;
  const int ws0  = prow*64 + ((ci ^ (prow & 7)) << 3);
  const int ws1  = ws0 + 32*64;
  const int csw  = (((4*(c & 1) + g) ^ ((c >> 1) & 7)) << 3);

  uint4 ar0, ar1, brr;
  #define ISSUE_OUT(KT) do{ \
    ar0 = *(const uint4*)(Abf + (size_t)(m0 + lr)*DM + (KT) + koff); \
    ar1 = *(const uint4*)(Abf + (size_t)(m0 + lr + 64)*DM + (KT) + koff); \
    brr = *(const uint4*)(Bth + (size_t)(n0 + lr)*DM + (KT) + koff); \
  }while(0)

  ISSUE_OUT(0);
  for (int kt = 0; kt < DM; kt += 32){
    *(uint4*)&As[ws0] = ar0;
    *(uint4*)&As[ws1] = ar1;
    if (lr < 64) *(uint4*)&Bs[ws0] = brr;
    __syncthreads();
    if (kt + 32 < DM) ISSUE_OUT(kt + 32);

    bf8_t a_h[4];
    #pragma unroll
    for (int fm = 0; fm < 4; ++fm)
      a_h[fm] = *(const bf8_t*)&As[(32*wr + 8*fm + (c>>1))*64 + csw];
    #pragma unroll
    for (int fn = 0; fn < 2; ++fn){
      bf8_t b_h = *(const bf8_t*)&Bs[(16*wc + 8*fn + (c>>1))*64 + csw];
      #pragma unroll
      for (int fm = 0; fm < 4; ++fm)
        acc[fm][fn] = MFMA16(a_h[fm], b_h, acc[fm][fn]);
    }
    __syncthreads();
  }
  #undef ISSUE_OUT

  #pragma unroll
  for (int fm = 0; fm < 4; ++fm){
    #pragma unroll
    for (int fn = 0; fn < 2; ++fn){
      const int col = n0 + 32*wc + 16*fn + c;
      const float bb = bias[col];
      const int row0 = m0 + 64*wr + 16*fm + 4*g;
      #pragma unroll
      for (int r = 0; r < 4; ++r)
        outf[(size_t)(row0 + r)*DM + col] = acc[fm][fn][r] + bb;
    }
  }
}

// ---- Stats pass: QBLK=128 (512 thr, 8 waves), KVBLK=64, 1-term QK (Qh),
// plain-bf16 Q/K, prefetch. Per-block slotted partials (no memset, no atomics).
__global__ __launch_bounds__(512) void attn_stats_mfma(
    const ush* __restrict__ Qb, const ush* __restrict__ Kb,
    float* __restrict__ stats)
{
  __shared__ ush Khs[64*64];
  __shared__ float red[8][3];
  const int tid = threadIdx.x, lane = tid & 63, w = tid >> 6;   // w 0..7
  const int c = lane & 15, g = lane >> 4;
  const int fid = blockIdx.x;
  const int glob = (fid & 7)*64 + (fid >> 3);     // 512 blocks, XCD-chunked
  const int bh = glob >> 3, qb = glob & 7, q0 = qb*128;

  bf8_t qh[2];
  {
    const ush* qp = Qb + ((size_t)bh*SS + q0 + 16*w + c)*DKH + 8*g;
    qh[0] = *(const bf8_t*)(qp);
    qh[1] = *(const bf8_t*)(qp + 32);
  }

  float ssum = 0.f, rmax = -1e30f, lsum = 0.f, l2sum = 0.f;
  const int rr0 = tid >> 3, ci = tid & 7;         // 64 rows x 8 chunks

  uint4 k0;
  #define ISSUE_ST(KC) do{ \
    k0 = *(const uint4*)(Kb + ((size_t)bh*SS + (KC)*64 + rr0)*DKH + ci*8); \
  }while(0)

  ISSUE_ST(0);
  for (int kc = 0; kc < 16; ++kc){
    *(uint4*)&Khs[swz8(rr0, ci)] = k0;
    __syncthreads();
    if (kc < 15) ISSUE_ST(kc + 1);

    f32x4 sa[4];
    #pragma unroll
    for (int fn = 0; fn < 4; ++fn) sa[fn] = (f32x4){0.f,0.f,0.f,0.f};
    __builtin_amdgcn_s_setprio(1);
    #pragma unroll
    for (int fn = 0; fn < 4; ++fn){
      #pragma unroll
      for (int ds = 0; ds < 2; ++ds){
        bf8_t ah = *(const bf8_t*)&Khs[swz8(16*fn + c, g + 4*ds)];
        sa[fn] = MFMA16(ah, qh[ds], sa[fn]);      // 1-term: Kh . Qh
      }
    }
    __builtin_amdgcn_s_setprio(0);
    #pragma unroll
    for (int fn = 0; fn < 4; ++fn){
      #pragma unroll
      for (int r = 0; r < 4; ++r){
        float s = sa[fn][r] * 0.125f;
        ssum += s;
        rmax = fmaxf(rmax, s);
        float e = exp2f(s * 0.7213475204f);       // exp(s/2); |s|<50 fp32-safe
        lsum += e;
        l2sum = fmaf(e, e, l2sum);
      }
    }
    __syncthreads();
  }
  #undef ISSUE_ST

  rmax  = fmaxf(rmax, __shfl_xor(rmax, 16, 64));
  rmax  = fmaxf(rmax, __shfl_xor(rmax, 32, 64));
  lsum  += __shfl_xor(lsum, 16, 64);   lsum  += __shfl_xor(lsum, 32, 64);
  l2sum += __shfl_xor(l2sum, 16, 64);  l2sum += __shfl_xor(l2sum, 32, 64);
  float varc = (l2sum/(lsum*lsum) - (1.0f/1024.f)) * (1.0f/1023.f);
  float a0 = ssum, a1 = rmax * 0.25f, a2 = varc * 0.25f;
  #pragma unroll
  for (int off = 1; off < 64; off <<= 1){
    a0 += __shfl_xor(a0, off, 64);
    a1 += __shfl_xor(a1, off, 64);
    a2 += __shfl_xor(a2, off, 64);
  }
  if (lane == 0){ red[w][0] = a0; red[w][1] = a1; red[w][2] = a2; }
  __syncthreads();
  if (tid == 0){
    float r0 = 0.f, r1 = 0.f, r2 = 0.f;
    #pragma unroll
    for (int i = 0; i < 8; ++i){ r0 += red[i][0]; r1 += red[i][1]; r2 += red[i][2]; }
    float* sp = stats + (size_t)(bh*8 + qb)*4;    // per-block slot, plain stores
    sp[0] = r0; sp[1] = r1; sp[2] = r2;
  }
}

// ---- Flash pass: QBLK=128 (512 thr), KVBLK=64 (16 iters), swapped QK^T
// 1-term (Kh . Qh), plain-bf16 Q/K, exp2, defer-max, swizzled LDS, prefetch.
// LDS = 32 KB. Time-MLP in prologue (sums 8 stat slots), lane-parallel.
__global__ __launch_bounds__(512) void attn_flash_mfma(
    const ush* __restrict__ Qb, const ush* __restrict__ Kb,
    const ush* __restrict__ Vt, const float* __restrict__ stats,
    const float* __restrict__ Wt1, const float* __restrict__ bt1,
    const float* __restrict__ Wt2, const float* __restrict__ bt2,
    ush* __restrict__ aout)
{
  __shared__ ush Khs[64*64], Vts[64*64], Ps[128*64];
  __shared__ float tshare;
  const int tid = threadIdx.x, lane = tid & 63, w = tid >> 6;   // w 0..7
  const int c = lane & 15, g = lane >> 4;
  const int fid = blockIdx.x;
  const int glob = (fid & 7)*64 + (fid >> 3);     // 512 blocks, XCD-chunked
  const int bh = glob >> 3, q0 = (glob & 7)*128;

  // ---- lane-parallel time-MLP: lane j computes hidden unit j; partials
  // summed from the 8 per-qb slots (deterministic order).
  if (tid < 16){
    const float* sp = stats + (size_t)bh*32;
    float s0 = 0.f, s1 = 0.f, s2 = 0.f;
    #pragma unroll
    for (int qb = 0; qb < 8; ++qb){
      s0 += sp[qb*4 + 0]; s1 += sp[qb*4 + 1]; s2 += sp[qb*4 + 2];
    }
    float mean = fminf(fmaxf(s0 * (1.f/(1024.f*1024.f)), -10.f), 10.f);
    float mx   = fminf(fmaxf(s1 * (1.f/1024.f), -10.f), 10.f);
    float ent  = fminf(fmaxf(s2 * (1.f/1024.f),   0.f),  1.f);
    float h = tanhf(mean*Wt1[tid] + mx*Wt1[16+tid] + ent*Wt1[32+tid] + bt1[tid])
              * Wt2[tid];
    h += __shfl_xor(h, 1, 64);
    h += __shfl_xor(h, 2, 64);
    h += __shfl_xor(h, 4, 64);
    h += __shfl_xor(h, 8, 64);
    if (tid == 0){
      float raw = h + bt2[0];
      float sig = 1.f / (1.f + expf(-raw));
      float t = 0.01f + sig * 1.99f;
      t = fminf(fminf(fmaxf(t, 0.01f), 2.0f), 0.85f);
      tshare = (0.5f / t) * 1.44269504f;          // exp2 domain
    }
  }

  bf8_t qh[2];
  {
    const ush* qp = Qb + ((size_t)bh*SS + q0 + 16*w + c)*DKH + 8*g;
    qh[0] = *(const bf8_t*)(qp);
    qh[1] = *(const bf8_t*)(qp + 32);
  }

  f32x4 o[4];
  #pragma unroll
  for (int i = 0; i < 4; ++i) o[i] = (f32x4){0.f,0.f,0.f,0.f};
  float m = -INFINITY, lpart = 0.f;

  const int rr0 = tid >> 3, ci = tid & 7;         // 64 rows x 8 chunks

  uint4 k0, vr0;
  #define ISSUE_FL(KC) do{ \
    k0  = *(const uint4*)(Kb + ((size_t)bh*SS + (KC)*64 + rr0)*DKH + ci*8); \
    vr0 = *(const uint4*)(Vt + ((size_t)bh*DKH + rr0)*SS + (KC)*64 + ci*8); \
  }while(0)

  ISSUE_FL(0);
  *(uint4*)&Khs[swz8(rr0, ci)] = k0;
  *(uint4*)&Vts[swz8(rr0, ci)] = vr0;
  __syncthreads();                                 // staging + tshare visible
  const float tsc2 = tshare;

  for (int kc = 0; kc < 16; ++kc){
    if (kc){
      *(uint4*)&Khs[swz8(rr0, ci)] = k0;
      *(uint4*)&Vts[swz8(rr0, ci)] = vr0;
      __syncthreads();
    }
    if (kc < 15) ISSUE_FL(kc + 1);

    f32x4 sa[4];
    #pragma unroll
    for (int fn = 0; fn < 4; ++fn) sa[fn] = (f32x4){0.f,0.f,0.f,0.f};
    __builtin_amdgcn_s_setprio(1);
    #pragma unroll
    for (int fn = 0; fn < 4; ++fn){
      #pragma unroll
      for (int ds = 0; ds < 2; ++ds){
        bf8_t ah = *(const bf8_t*)&Khs[swz8(16*fn + c, g + 4*ds)];
        sa[fn] = MFMA16(ah, qh[ds], sa[fn]);   // 1-term: Kh . Qh
      }
    }
    __builtin_amdgcn_s_setprio(0);

    // lane-local max over own 16 kv; shuffles only in the rare rescale path
    float pmaxr = -1e30f;
    #pragma unroll
    for (int fn = 0; fn < 4; ++fn)
      #pragma unroll
      for (int r = 0; r < 4; ++r) pmaxr = fmaxf(pmaxr, sa[fn][r]);

    if (!__all(pmaxr * tsc2 <= m + 30.f)){     // fires ~once (kc=0)
      pmaxr = fmaxf(pmaxr, __shfl_xor(pmaxr, 16, 64));
      pmaxr = fmaxf(pmaxr, __shfl_xor(pmaxr, 32, 64));
      float pmax = pmaxr * tsc2;
      float mn = fmaxf(m, pmax);
      float sc = exp2f(m - mn);
      m = mn;
      lpart *= sc;
      #pragma unroll
      for (int r = 0; r < 4; ++r){
        float so = __shfl(sc, 4*g + r, 16);    // sc of q-row 4g+r (c'=4g+r)
        #pragma unroll
        for (int fn = 0; fn < 4; ++fn) o[fn][r] *= so;
      }
    }

    const float mneg = -m;
    #pragma unroll
    for (int fn = 0; fn < 4; ++fn){
      float e0 = exp2f(fmaf(sa[fn][0], tsc2, mneg));
      float e1 = exp2f(fmaf(sa[fn][1], tsc2, mneg));
      float e2 = exp2f(fmaf(sa[fn][2], tsc2, mneg));
      float e3 = exp2f(fmaf(sa[fn][3], tsc2, mneg));
      lpart += (e0 + e1) + (e2 + e3);
      uint2 pk;
      pk.x = pk2(e0, e1);
      pk.y = pk2(e2, e3);
      const int q4 = 4*fn + g;
      const int addr = (16*w + c)*64 + ((((q4 >> 1) ^ (c & 7)) << 3)) + (q4 & 1)*4;
      *(uint2*)&Ps[addr] = pk;
    }

    __builtin_amdgcn_s_setprio(1);
    #pragma unroll
    for (int kvs = 0; kvs < 2; ++kvs){
      bf8_t pa = *(const bf8_t*)&Ps[swz8(16*w + c, g + 4*kvs)];
      #pragma unroll
      for (int fn = 0; fn < 4; ++fn){
        bf8_t vb = *(const bf8_t*)&Vts[swz8(16*fn + c, g + 4*kvs)];
        o[fn] = MFMA16(pa, vb, o[fn]);
      }
    }
    __builtin_amdgcn_s_setprio(0);
    __syncthreads();
  }
  #undef ISSUE_FL

  lpart += __shfl_xor(lpart, 16, 64);
  lpart += __shfl_xor(lpart, 32, 64);
  const int b = bh >> 4, hd = bh & 15;
  #pragma unroll
  for (int r = 0; r < 4; ++r){
    float linv = 1.f / __shfl(lpart, 4*g + r, 16);   // l of q-row 4g+r
    const int q = q0 + 16*w + 4*g + r;
    #pragma unroll
    for (int fn = 0; fn < 4; ++fn)
      aout[((size_t)(b*SS + q))*DM + hd*DKH + 16*fn + c] = f2bf(o[fn][r] * linv);
  }
}

extern "C" void kernel_launch(void* const* d_in, const int* in_sizes, int n_in,
                              void* d_out, int out_size, void* d_ws, size_t ws_size,
                              hipStream_t stream)
{
  const float* query = (const float*)d_in[0];
  const float* key   = (const float*)d_in[1];
  const float* value = (const float*)d_in[2];
  const float* Wq = (const float*)d_in[3];
  const float* bq = (const float*)d_in[4];
  const float* Wk = (const float*)d_in[5];
  const float* bk = (const float*)d_in[6];
  const float* Wv = (const float*)d_in[7];
  const float* bv = (const float*)d_in[8];
  const float* Wo = (const float*)d_in[9];
  const float* bo = (const float*)d_in[10];
  const float* Wt1 = (const float*)d_in[11];
  const float* bt1 = (const float*)d_in[12];
  const float* Wt2 = (const float*)d_in[13];
  const float* bt2 = (const float*)d_in[14];

  const size_t E = (size_t)NB*SS*DM;       // 4,194,304
  const size_t WE = (size_t)DM*DM;

  ush* Qbb = (ush*)d_ws;                   // E ush (plain bf16)
  ush* Kbb = Qbb + E;                      // E ush
  ush* Vtb = Kbb + E;                      // E ush (b*16+h, dk, s)
  ush* Aob = Vtb + E;                      // E ush  -- also aliased as xqb
  ush* xqb = Aob;                          // alias: consumed before Aob written
  ush* xkb = Aob + E;
  ush* xvb = xkb + E;
  ush* Wqh = xvb + E;
  ush* Wkh = Wqh + WE;
  ush* Wvh = Wkh + WE;
  ush* Woh = Wvh + WE;
  float* stats = (float*)(Woh + WE);       // 64 bh x 8 qb x 4 floats = 2048

  xconv<<<dim3(2048, 3), 256, 0, stream>>>(query, key, value, xqb, xkb, xvb);

  dim3 wb(32, 8), wg(32, 32, 4);
  wconv4<<<wg, wb, 0, stream>>>(Wq, Wk, Wv, Wo, Wqh, Wkh, Wvh, Woh);

  proj_qkv<<<768, 256, 0, stream>>>(xqb, xkb, xvb,
      Wqh, Wkh, Wvh, bq, bk, bv, Qbb, Kbb, Vtb);

  attn_stats_mfma<<<512, 512, 0, stream>>>(Qbb, Kbb, stats);
  attn_flash_mfma<<<512, 512, 0, stream>>>(Qbb, Kbb, Vtb, stats,
      Wt1, bt1, Wt2, bt2, Aob);

  gemm_out<<<512, 256, 0, stream>>>(Aob, Woh, bo, (float*)d_out);
}

// Round 24
// 137.058 us; speedup vs baseline: 1.1765x; 1.0130x over previous
//
#include <hip/hip_runtime.h>
#include <hip/hip_bf16.h>
#include <math.h>

#define SS   1024
#define DM   1024
#define NH   16
#define DKH  64
#define NB   4
#define NBH  64

typedef unsigned short ush;
typedef unsigned int uint32;
typedef __attribute__((ext_vector_type(8))) short bf8_t;   // 8 bf16 = 4 VGPR
typedef __attribute__((ext_vector_type(4))) float f32x4;
#define MFMA16(a,b,c) __builtin_amdgcn_mfma_f32_16x16x32_bf16((a),(b),(c),0,0,0)

__device__ __forceinline__ ush f2bf(float x){ return __bfloat16_as_ushort(__float2bfloat16(x)); }
__device__ __forceinline__ uint32 pk2(float a, float b){
  return (uint32)f2bf(a) | ((uint32)f2bf(b) << 16);
}
// [rows][64]-ush tile, XOR swizzle on 16B chunks
__device__ __forceinline__ int swz8(int row, int chunk){
  return row*64 + (((chunk) ^ (row & 7)) << 3);
}

// ---- x fp32 -> bf16 (hi only)
__global__ __launch_bounds__(256) void xconv(
    const float* __restrict__ q, const float* __restrict__ k, const float* __restrict__ v,
    ush* __restrict__ xq, ush* __restrict__ xk, ush* __restrict__ xv)
{
  const float* src = (blockIdx.y==0)?q:(blockIdx.y==1)?k:v;
  ush* dst = (blockIdx.y==0)?xq:(blockIdx.y==1)?xk:xv;
  const size_t i = ((size_t)blockIdx.x*256 + threadIdx.x)*8;
  float4 a = *(const float4*)&src[i];
  float4 b = *(const float4*)&src[i+4];
  uint4 o;
  o.x = pk2(a.x, a.y); o.y = pk2(a.z, a.w);
  o.z = pk2(b.x, b.y); o.w = pk2(b.z, b.w);
  *(uint4*)&dst[i] = o;
}

// ---- weight convert: W (K x N) fp32 -> Wt (N x K) bf16 hi only
__global__ void wconv4(const float* __restrict__ W0, const float* __restrict__ W1,
                       const float* __restrict__ W2, const float* __restrict__ W3,
                       ush* __restrict__ H0, ush* __restrict__ H1,
                       ush* __restrict__ H2, ush* __restrict__ H3)
{
  __shared__ float T[32][33];
  const int tx = threadIdx.x, ty = threadIdx.y;    // (32,8)
  const int z = blockIdx.z;
  const float* W = (z==0)?W0:(z==1)?W1:(z==2)?W2:W3;
  ush* H = (z==0)?H0:(z==1)?H1:(z==2)?H2:H3;
  const int k0 = blockIdx.y*32, n0 = blockIdx.x*32;
  #pragma unroll
  for (int i = 0; i < 4; ++i){
    int r = ty + 8*i;
    T[r][tx] = W[(size_t)(k0 + r)*DM + n0 + tx];
  }
  __syncthreads();
  #pragma unroll
  for (int i = 0; i < 4; ++i){
    int r = ty + 8*i;              // n-local
    H[(size_t)(n0 + r)*DM + k0 + tx] = f2bf(T[tx][r]);
  }
}

// ---- fused Q/K/V projection: BK=32, 1-term (W hi), double-buffered LDS via
// global_load_lds width-16 with pre-swizzled per-lane SOURCE addresses.
// Q/K out plain bf16 (b*16+h, s, dk); V out bf16 transposed (b*16+h, dk, s).
__global__ __launch_bounds__(256) void proj_qkv(
    const ush* __restrict__ xq, const ush* __restrict__ xk, const ush* __restrict__ xv,
    const ush* __restrict__ Wqh, const ush* __restrict__ Wkh, const ush* __restrict__ Wvh,
    const float* __restrict__ bq, const float* __restrict__ bk,
    const float* __restrict__ bv,
    ush* __restrict__ Qb, ush* __restrict__ Kb, ush* __restrict__ Vt)
{
  // staging: 2 buffers x (As 4096 | Bhs 4096) = 32 KB; V-epilogue 4*4224 ush
  __shared__ ush SMEM[16896];

  const int fid = blockIdx.x;
  const int glob = (fid & 7)*96 + (fid >> 3);  // XCD-contiguous chunks of 96
  const int z = glob >> 8, rem = glob & 255;
  const int m0 = (rem >> 3) * 128, n0 = (rem & 7) * 128;

  const ush* A  = (z==0) ? xq  : (z==1) ? xk  : xv;
  const ush* Bh = (z==0) ? Wqh : (z==1) ? Wkh : Wvh;

  const int tid = threadIdx.x;
  const int lane = tid & 63, w = tid >> 6;
  const int c = lane & 15, g = lane >> 4;
  const int wr = w >> 1, wc = w & 1;

  f32x4 acc[4][4];
  #pragma unroll
  for (int i = 0; i < 4; ++i)
    #pragma unroll
    for (int j = 0; j < 4; ++j) acc[i][j] = (f32x4){0.f,0.f,0.f,0.f};

  const int prow0 = w*16 + (lane >> 3), prow1 = prow0 + 8;
  const int jj = lane & 7;
  const int sg0 = jj ^ (prow0 & 7), sg1 = jj ^ (prow1 & 7);
  const size_t aoff0 = (size_t)(2*prow0 + (sg0 >> 2))*DM + (sg0 & 3)*8;
  const size_t aoff1 = (size_t)(2*prow1 + (sg1 >> 2))*DM + (sg1 & 3)*8;
  const ush* Aab = A  + (size_t)m0*DM;
  const ush* Bhb = Bh + (size_t)n0*DM;
  const int lb0 = w*1024, lb1 = w*1024 + 512;   // wave-uniform LDS bases (ush)

#define GLL(GP, LIDX) __builtin_amdgcn_global_load_lds( \
    (const __attribute__((address_space(1))) unsigned int*)(GP), \
    (__attribute__((address_space(3))) unsigned int*)(&SMEM[LIDX]), 16, 0, 0)

#define ISSUE_PROJ(BUFO, KT) do{ \
    GLL(Aab + aoff0 + (KT), (BUFO) + lb0); \
    GLL(Aab + aoff1 + (KT), (BUFO) + lb1); \
    GLL(Bhb + aoff0 + (KT), (BUFO) + 4096 + lb0); \
    GLL(Bhb + aoff1 + (KT), (BUFO) + 4096 + lb1); \
  }while(0)

  const int csw = (((4*(c & 1) + g) ^ ((c >> 1) & 7)) << 3);

  ISSUE_PROJ(0, 0);
  int cur = 0;
  for (int kt = 0; kt < DM; kt += 32){
    __syncthreads();                       // drains vmcnt -> buf[cur] ready
    if (kt + 32 < DM) ISSUE_PROJ((cur ^ 1)*8192, kt + 32);

    const ush* As  = SMEM + cur*8192;
    const ush* Bhs = As + 4096;

    bf8_t a_h[4];
    #pragma unroll
    for (int fm = 0; fm < 4; ++fm)
      a_h[fm] = *(const bf8_t*)&As[(32*wr + 8*fm + (c>>1))*64 + csw];
    __builtin_amdgcn_s_setprio(1);
    #pragma unroll
    for (int fn = 0; fn < 4; ++fn){
      bf8_t b_h = *(const bf8_t*)&Bhs[(32*wc + 8*fn + (c>>1))*64 + csw];
      #pragma unroll
      for (int fm = 0; fm < 4; ++fm)
        acc[fm][fn] = MFMA16(a_h[fm], b_h, acc[fm][fn]);
    }
    __builtin_amdgcn_s_setprio(0);
    cur ^= 1;
  }
#undef ISSUE_PROJ
#undef GLL

  if (z < 2){
    ush* O = (z==0) ? Qb : Kb;
    const float* bias = (z==0) ? bq : bk;
    #pragma unroll
    for (int fm = 0; fm < 4; ++fm){
      #pragma unroll
      for (int fn = 0; fn < 4; ++fn){
        const int col = n0 + 64*wc + 16*fn + c;
        const float bb = bias[col];
        const int row0 = m0 + 64*wr + 16*fm + 4*g;
        const int hd = col >> 6, d = col & 63;
        #pragma unroll
        for (int r = 0; r < 4; ++r){
          const int row = row0 + r;
          const int b = row >> 10, s = row & 1023;
          O[((size_t)(b*NH + hd)*SS + s)*DKH + d] = f2bf(acc[fm][fn][r] + bb);
        }
      }
    }
  } else {
    // V: transpose wave's 64(s) x 64(d) sub-tile through LDS -> coalesced (d,s)
    __syncthreads();                      // all waves done reading staging LDS
    ush* Vep = SMEM + w*4224;             // 64 rows(d) x 66 cols(s)
    #pragma unroll
    for (int fm = 0; fm < 4; ++fm){
      #pragma unroll
      for (int fn = 0; fn < 4; ++fn){
        const float bb = bv[n0 + 64*wc + 16*fn + c];
        #pragma unroll
        for (int r = 0; r < 4; ++r)
          Vep[(16*fn + c)*66 + 16*fm + 4*g + r] = f2bf(acc[fm][fn][r] + bb);
      }
    }
    const int b = m0 >> 10;
    const int s0 = (m0 & 1023) + 64*wr;
    const int hd = (n0 >> 6) + wc;
    const size_t vbase = ((size_t)(b*NH + hd))*DKH*SS;
    #pragma unroll
    for (int it = 0; it < 8; ++it){
      const int dr = 8*it + (lane >> 3);
      const int sc = (lane & 7)*8;
      uint4 vv = *(const uint4*)&Vep[dr*66 + sc];
      *(uint4*)&Vt[vbase + (size_t)dr*SS + s0 + sc] = vv;
    }
  }
}

// ---- output projection: C = A(bf16) @ Wo^T + bo, 128x64 tile, paired-row LDS
__global__ __launch_bounds__(256) void gemm_out(
    const ush* __restrict__ Abf, const ush* __restrict__ Bth,
    const float* __restrict__ bias, float* __restrict__ outf)
{
  __shared__ ush As[4096], Bs[2048];

  const int fid = blockIdx.x;
  const int glob = (fid & 7)*64 + (fid >> 3);
  const int m0 = (glob >> 4)*128, n0 = (glob & 15)*64;

  const int tid = threadIdx.x;
  const int lane = tid & 63, w = tid >> 6;
  const int c = lane & 15, g = lane >> 4;
  const int wr = w >> 1, wc = w & 1;

  f32x4 acc[4][2];
  #pragma unroll
  for (int i = 0; i < 4; ++i){ acc[i][0] = (f32x4){0,0,0,0}; acc[i][1] = (f32x4){0,0,0,0}; }

  const int prow = tid >> 3, ci = tid & 7;
  const int lr   = 2*prow + (ci >> 2);
  const int koff = (ci & 3) << 3;
  const int ws0  = prow*64 + ((ci ^ (prow & 7)) << 3);
  const int ws1  = ws0 + 32*64;
  const int csw  = (((4*(c & 1) + g) ^ ((c >> 1) & 7)) << 3);

  uint4 ar0, ar1, brr;
  #define ISSUE_OUT(KT) do{ \
    ar0 = *(const uint4*)(Abf + (size_t)(m0 + lr)*DM + (KT) + koff); \
    ar1 = *(const uint4*)(Abf + (size_t)(m0 + lr + 64)*DM + (KT) + koff); \
    brr = *(const uint4*)(Bth + (size_t)(n0 + lr)*DM + (KT) + koff); \
  }while(0)

  ISSUE_OUT(0);
  for (int kt = 0; kt < DM; kt += 32){
    *(uint4*)&As[ws0] = ar0;
    *(uint4*)&As[ws1] = ar1;
    if (lr < 64) *(uint4*)&Bs[ws0] = brr;
    __syncthreads();
    if (kt + 32 < DM) ISSUE_OUT(kt + 32);

    bf8_t a_h[4];
    #pragma unroll
    for (int fm = 0; fm < 4; ++fm)
      a_h[fm] = *(const bf8_t*)&As[(32*wr + 8*fm + (c>>1))*64 + csw];
    #pragma unroll
    for (int fn = 0; fn < 2; ++fn){
      bf8_t b_h = *(const bf8_t*)&Bs[(16*wc + 8*fn + (c>>1))*64 + csw];
      #pragma unroll
      for (int fm = 0; fm < 4; ++fm)
        acc[fm][fn] = MFMA16(a_h[fm], b_h, acc[fm][fn]);
    }
    __syncthreads();
  }
  #undef ISSUE_OUT

  #pragma unroll
  for (int fm = 0; fm < 4; ++fm){
    #pragma unroll
    for (int fn = 0; fn < 2; ++fn){
      const int col = n0 + 32*wc + 16*fn + c;
      const float bb = bias[col];
      const int row0 = m0 + 64*wr + 16*fm + 4*g;
      #pragma unroll
      for (int r = 0; r < 4; ++r)
        outf[(size_t)(row0 + r)*DM + col] = acc[fm][fn][r] + bb;
    }
  }
}

// ---- Stats pass: QBLK=128 (512 thr, 8 waves), KVBLK=64, 1-term QK (Qh),
// plain-bf16 Q/K, double-buffered K LDS (1 barrier/iter), slotted partials.
__global__ __launch_bounds__(512) void attn_stats_mfma(
    const ush* __restrict__ Qb, const ush* __restrict__ Kb,
    float* __restrict__ stats)
{
  __shared__ ush Khs[2*4096];
  __shared__ float red[8][3];
  const int tid = threadIdx.x, lane = tid & 63, w = tid >> 6;   // w 0..7
  const int c = lane & 15, g = lane >> 4;
  const int fid = blockIdx.x;
  const int glob = (fid & 7)*64 + (fid >> 3);     // 512 blocks, XCD-chunked
  const int bh = glob >> 3, qb = glob & 7, q0 = qb*128;

  bf8_t qh[2];
  {
    const ush* qp = Qb + ((size_t)bh*SS + q0 + 16*w + c)*DKH + 8*g;
    qh[0] = *(const bf8_t*)(qp);
    qh[1] = *(const bf8_t*)(qp + 32);
  }

  float ssum = 0.f, rmax = -1e30f, lsum = 0.f, l2sum = 0.f;
  const int rr0 = tid >> 3, ci = tid & 7;         // 64 rows x 8 chunks

  uint4 k0;
  #define ISSUE_ST(KC) do{ \
    k0 = *(const uint4*)(Kb + ((size_t)bh*SS + (KC)*64 + rr0)*DKH + ci*8); \
  }while(0)

  // prologue: tile0 -> buf0; issue tile1; one barrier
  ISSUE_ST(0);
  *(uint4*)&Khs[swz8(rr0, ci)] = k0;
  ISSUE_ST(1);
  __syncthreads();

  for (int kc = 0; kc < 16; ++kc){
    // write tile kc+1 into buf[(kc+1)&1] (prior reads separated by barrier)
    if (kc < 15) *(uint4*)&Khs[((kc+1)&1)*4096 + swz8(rr0, ci)] = k0;
    if (kc < 14) ISSUE_ST(kc + 2);

    const ush* ks = Khs + (kc&1)*4096;
    f32x4 sa[4];
    #pragma unroll
    for (int fn = 0; fn < 4; ++fn) sa[fn] = (f32x4){0.f,0.f,0.f,0.f};
    __builtin_amdgcn_s_setprio(1);
    #pragma unroll
    for (int fn = 0; fn < 4; ++fn){
      #pragma unroll
      for (int ds = 0; ds < 2; ++ds){
        bf8_t ah = *(const bf8_t*)&ks[swz8(16*fn + c, g + 4*ds)];
        sa[fn] = MFMA16(ah, qh[ds], sa[fn]);      // 1-term: Kh . Qh
      }
    }
    __builtin_amdgcn_s_setprio(0);
    #pragma unroll
    for (int fn = 0; fn < 4; ++fn){
      #pragma unroll
      for (int r = 0; r < 4; ++r){
        float s = sa[fn][r] * 0.125f;
        ssum += s;
        rmax = fmaxf(rmax, s);
        float e = exp2f(s * 0.7213475204f);       // exp(s/2); |s|<50 fp32-safe
        lsum += e;
        l2sum = fmaf(e, e, l2sum);
      }
    }
    if (kc < 15) __syncthreads();
  }
  #undef ISSUE_ST

  rmax  = fmaxf(rmax, __shfl_xor(rmax, 16, 64));
  rmax  = fmaxf(rmax, __shfl_xor(rmax, 32, 64));
  lsum  += __shfl_xor(lsum, 16, 64);   lsum  += __shfl_xor(lsum, 32, 64);
  l2sum += __shfl_xor(l2sum, 16, 64);  l2sum += __shfl_xor(l2sum, 32, 64);
  float varc = (l2sum/(lsum*lsum) - (1.0f/1024.f)) * (1.0f/1023.f);
  float a0 = ssum, a1 = rmax * 0.25f, a2 = varc * 0.25f;
  #pragma unroll
  for (int off = 1; off < 64; off <<= 1){
    a0 += __shfl_xor(a0, off, 64);
    a1 += __shfl_xor(a1, off, 64);
    a2 += __shfl_xor(a2, off, 64);
  }
  if (lane == 0){ red[w][0] = a0; red[w][1] = a1; red[w][2] = a2; }
  __syncthreads();
  if (tid == 0){
    float r0 = 0.f, r1 = 0.f, r2 = 0.f;
    #pragma unroll
    for (int i = 0; i < 8; ++i){ r0 += red[i][0]; r1 += red[i][1]; r2 += red[i][2]; }
    float* sp = stats + (size_t)(bh*8 + qb)*4;    // per-block slot, plain stores
    sp[0] = r0; sp[1] = r1; sp[2] = r2;
  }
}

// ---- Flash pass: QBLK=128 (512 thr), KVBLK=64 (16 iters), swapped QK^T
// 1-term (Kh . Qh), plain-bf16 Q/K, exp2, defer-max, swizzled LDS,
// double-buffered K/V (1 barrier/iter). LDS = 48 KB. Time-MLP in prologue.
__global__ __launch_bounds__(512) void attn_flash_mfma(
    const ush* __restrict__ Qb, const ush* __restrict__ Kb,
    const ush* __restrict__ Vt, const float* __restrict__ stats,
    const float* __restrict__ Wt1, const float* __restrict__ bt1,
    const float* __restrict__ Wt2, const float* __restrict__ bt2,
    ush* __restrict__ aout)
{
  __shared__ ush Khs[2*4096], Vts[2*4096], Ps[128*64];
  __shared__ float tshare;
  const int tid = threadIdx.x, lane = tid & 63, w = tid >> 6;   // w 0..7
  const int c = lane & 15, g = lane >> 4;
  const int fid = blockIdx.x;
  const int glob = (fid & 7)*64 + (fid >> 3);     // 512 blocks, XCD-chunked
  const int bh = glob >> 3, q0 = (glob & 7)*128;

  // ---- lane-parallel time-MLP: lane j computes hidden unit j; partials
  // summed from the 8 per-qb slots (deterministic order).
  if (tid < 16){
    const float* sp = stats + (size_t)bh*32;
    float s0 = 0.f, s1 = 0.f, s2 = 0.f;
    #pragma unroll
    for (int qb = 0; qb < 8; ++qb){
      s0 += sp[qb*4 + 0]; s1 += sp[qb*4 + 1]; s2 += sp[qb*4 + 2];
    }
    float mean = fminf(fmaxf(s0 * (1.f/(1024.f*1024.f)), -10.f), 10.f);
    float mx   = fminf(fmaxf(s1 * (1.f/1024.f), -10.f), 10.f);
    float ent  = fminf(fmaxf(s2 * (1.f/1024.f),   0.f),  1.f);
    float h = tanhf(mean*Wt1[tid] + mx*Wt1[16+tid] + ent*Wt1[32+tid] + bt1[tid])
              * Wt2[tid];
    h += __shfl_xor(h, 1, 64);
    h += __shfl_xor(h, 2, 64);
    h += __shfl_xor(h, 4, 64);
    h += __shfl_xor(h, 8, 64);
    if (tid == 0){
      float raw = h + bt2[0];
      float sig = 1.f / (1.f + expf(-raw));
      float t = 0.01f + sig * 1.99f;
      t = fminf(fminf(fmaxf(t, 0.01f), 2.0f), 0.85f);
      tshare = (0.5f / t) * 1.44269504f;          // exp2 domain
    }
  }

  bf8_t qh[2];
  {
    const ush* qp = Qb + ((size_t)bh*SS + q0 + 16*w + c)*DKH + 8*g;
    qh[0] = *(const bf8_t*)(qp);
    qh[1] = *(const bf8_t*)(qp + 32);
  }

  f32x4 o[4];
  #pragma unroll
  for (int i = 0; i < 4; ++i) o[i] = (f32x4){0.f,0.f,0.f,0.f};
  float m = -INFINITY, lpart = 0.f;

  const int rr0 = tid >> 3, ci = tid & 7;         // 64 rows x 8 chunks

  uint4 k0, vr0;
  #define ISSUE_FL(KC) do{ \
    k0  = *(const uint4*)(Kb + ((size_t)bh*SS + (KC)*64 + rr0)*DKH + ci*8); \
    vr0 = *(const uint4*)(Vt + ((size_t)bh*DKH + rr0)*SS + (KC)*64 + ci*8); \
  }while(0)

  // prologue: tile0 -> buf0; issue tile1; one barrier (also publishes tshare)
  ISSUE_FL(0);
  *(uint4*)&Khs[swz8(rr0, ci)] = k0;
  *(uint4*)&Vts[swz8(rr0, ci)] = vr0;
  ISSUE_FL(1);
  __syncthreads();
  const float tsc2 = tshare;

  for (int kc = 0; kc < 16; ++kc){
    // write tile kc+1 into buf[(kc+1)&1]; prior reads separated by barrier
    if (kc < 15){
      *(uint4*)&Khs[((kc+1)&1)*4096 + swz8(rr0, ci)] = k0;
      *(uint4*)&Vts[((kc+1)&1)*4096 + swz8(rr0, ci)] = vr0;
    }
    if (kc < 14) ISSUE_FL(kc + 2);

    const ush* ks = Khs + (kc&1)*4096;
    const ush* vs = Vts + (kc&1)*4096;

    f32x4 sa[4];
    #pragma unroll
    for (int fn = 0; fn < 4; ++fn) sa[fn] = (f32x4){0.f,0.f,0.f,0.f};
    __builtin_amdgcn_s_setprio(1);
    #pragma unroll
    for (int fn = 0; fn < 4; ++fn){
      #pragma unroll
      for (int ds = 0; ds < 2; ++ds){
        bf8_t ah = *(const bf8_t*)&ks[swz8(16*fn + c, g + 4*ds)];
        sa[fn] = MFMA16(ah, qh[ds], sa[fn]);   // 1-term: Kh . Qh
      }
    }
    __builtin_amdgcn_s_setprio(0);

    // lane-local max over own 16 kv; shuffles only in the rare rescale path
    float pmaxr = -1e30f;
    #pragma unroll
    for (int fn = 0; fn < 4; ++fn)
      #pragma unroll
      for (int r = 0; r < 4; ++r) pmaxr = fmaxf(pmaxr, sa[fn][r]);

    if (!__all(pmaxr * tsc2 <= m + 30.f)){     // fires ~once (kc=0)
      pmaxr = fmaxf(pmaxr, __shfl_xor(pmaxr, 16, 64));
      pmaxr = fmaxf(pmaxr, __shfl_xor(pmaxr, 32, 64));
      float pmax = pmaxr * tsc2;
      float mn = fmaxf(m, pmax);
      float sc = exp2f(m - mn);
      m = mn;
      lpart *= sc;
      #pragma unroll
      for (int r = 0; r < 4; ++r){
        float so = __shfl(sc, 4*g + r, 16);    // sc of q-row 4g+r (c'=4g+r)
        #pragma unroll
        for (int fn = 0; fn < 4; ++fn) o[fn][r] *= so;
      }
    }

    const float mneg = -m;
    #pragma unroll
    for (int fn = 0; fn < 4; ++fn){
      float e0 = exp2f(fmaf(sa[fn][0], tsc2, mneg));
      float e1 = exp2f(fmaf(sa[fn][1], tsc2, mneg));
      float e2 = exp2f(fmaf(sa[fn][2], tsc2, mneg));
      float e3 = exp2f(fmaf(sa[fn][3], tsc2, mneg));
      lpart += (e0 + e1) + (e2 + e3);
      uint2 pk;
      pk.x = pk2(e0, e1);
      pk.y = pk2(e2, e3);
      const int q4 = 4*fn + g;
      const int addr = (16*w + c)*64 + ((((q4 >> 1) ^ (c & 7)) << 3)) + (q4 & 1)*4;
      *(uint2*)&Ps[addr] = pk;
    }

    // P rows (16w+c) are wave-local: no barrier needed before PV
    __builtin_amdgcn_s_setprio(1);
    #pragma unroll
    for (int kvs = 0; kvs < 2; ++kvs){
      bf8_t pa = *(const bf8_t*)&Ps[swz8(16*w + c, g + 4*kvs)];
      #pragma unroll
      for (int fn = 0; fn < 4; ++fn){
        bf8_t vb = *(const bf8_t*)&vs[swz8(16*fn + c, g + 4*kvs)];
        o[fn] = MFMA16(pa, vb, o[fn]);
      }
    }
    __builtin_amdgcn_s_setprio(0);
    if (kc < 15) __syncthreads();
  }
  #undef ISSUE_FL

  lpart += __shfl_xor(lpart, 16, 64);
  lpart += __shfl_xor(lpart, 32, 64);
  const int b = bh >> 4, hd = bh & 15;
  #pragma unroll
  for (int r = 0; r < 4; ++r){
    float linv = 1.f / __shfl(lpart, 4*g + r, 16);   // l of q-row 4g+r
    const int q = q0 + 16*w + 4*g + r;
    #pragma unroll
    for (int fn = 0; fn < 4; ++fn)
      aout[((size_t)(b*SS + q))*DM + hd*DKH + 16*fn + c] = f2bf(o[fn][r] * linv);
  }
}

extern "C" void kernel_launch(void* const* d_in, const int* in_sizes, int n_in,
                              void* d_out, int out_size, void* d_ws, size_t ws_size,
                              hipStream_t stream)
{
  const float* query = (const float*)d_in[0];
  const float* key   = (const float*)d_in[1];
  const float* value = (const float*)d_in[2];
  const float* Wq = (const float*)d_in[3];
  const float* bq = (const float*)d_in[4];
  const float* Wk = (const float*)d_in[5];
  const float* bk = (const float*)d_in[6];
  const float* Wv = (const float*)d_in[7];
  const float* bv = (const float*)d_in[8];
  const float* Wo = (const float*)d_in[9];
  const float* bo = (const float*)d_in[10];
  const float* Wt1 = (const float*)d_in[11];
  const float* bt1 = (const float*)d_in[12];
  const float* Wt2 = (const float*)d_in[13];
  const float* bt2 = (const float*)d_in[14];

  const size_t E = (size_t)NB*SS*DM;       // 4,194,304
  const size_t WE = (size_t)DM*DM;

  ush* Qbb = (ush*)d_ws;                   // E ush (plain bf16)
  ush* Kbb = Qbb + E;                      // E ush
  ush* Vtb = Kbb + E;                      // E ush (b*16+h, dk, s)
  ush* Aob = Vtb + E;                      // E ush  -- also aliased as xqb
  ush* xqb = Aob;                          // alias: consumed before Aob written
  ush* xkb = Aob + E;
  ush* xvb = xkb + E;
  ush* Wqh = xvb + E;
  ush* Wkh = Wqh + WE;
  ush* Wvh = Wkh + WE;
  ush* Woh = Wvh + WE;
  float* stats = (float*)(Woh + WE);       // 64 bh x 8 qb x 4 floats = 2048

  xconv<<<dim3(2048, 3), 256, 0, stream>>>(query, key, value, xqb, xkb, xvb);

  dim3 wb(32, 8), wg(32, 32, 4);
  wconv4<<<wg, wb, 0, stream>>>(Wq, Wk, Wv, Wo, Wqh, Wkh, Wvh, Woh);

  proj_qkv<<<768, 256, 0, stream>>>(xqb, xkb, xvb,
      Wqh, Wkh, Wvh, bq, bk, bv, Qbb, Kbb, Vtb);

  attn_stats_mfma<<<512, 512, 0, stream>>>(Qbb, Kbb, stats);
  attn_flash_mfma<<<512, 512, 0, stream>>>(Qbb, Kbb, Vtb, stats,
      Wt1, bt1, Wt2, bt2, Aob);

  gemm_out<<<512, 256, 0, stream>>>(Aob, Woh, bo, (float*)d_out);
}

// Round 25
// 135.749 us; speedup vs baseline: 1.1878x; 1.0096x over previous
//
#include <hip/hip_runtime.h>
#include <hip/hip_bf16.h>
#include <math.h>

#define SS   1024
#define DM   1024
#define NH   16
#define DKH  64
#define NB   4
#define NBH  64

typedef unsigned short ush;
typedef unsigned int uint32;
typedef __attribute__((ext_vector_type(8))) short bf8_t;   // 8 bf16 = 4 VGPR
typedef __attribute__((ext_vector_type(4))) float f32x4;
#define MFMA16(a,b,c) __builtin_amdgcn_mfma_f32_16x16x32_bf16((a),(b),(c),0,0,0)

__device__ __forceinline__ ush f2bf(float x){ return __bfloat16_as_ushort(__float2bfloat16(x)); }
__device__ __forceinline__ uint32 pk2(float a, float b){
  return (uint32)f2bf(a) | ((uint32)f2bf(b) << 16);
}
// [rows][64]-ush tile, XOR swizzle on 16B chunks
__device__ __forceinline__ int swz8(int row, int chunk){
  return row*64 + (((chunk) ^ (row & 7)) << 3);
}

// ---- x fp32 -> bf16 (hi only)
__global__ __launch_bounds__(256) void xconv(
    const float* __restrict__ q, const float* __restrict__ k, const float* __restrict__ v,
    ush* __restrict__ xq, ush* __restrict__ xk, ush* __restrict__ xv)
{
  const float* src = (blockIdx.y==0)?q:(blockIdx.y==1)?k:v;
  ush* dst = (blockIdx.y==0)?xq:(blockIdx.y==1)?xk:xv;
  const size_t i = ((size_t)blockIdx.x*256 + threadIdx.x)*8;
  float4 a = *(const float4*)&src[i];
  float4 b = *(const float4*)&src[i+4];
  uint4 o;
  o.x = pk2(a.x, a.y); o.y = pk2(a.z, a.w);
  o.z = pk2(b.x, b.y); o.w = pk2(b.z, b.w);
  *(uint4*)&dst[i] = o;
}

// ---- weight convert: W (K x N) fp32 -> Wt (N x K) bf16 hi only
__global__ void wconv4(const float* __restrict__ W0, const float* __restrict__ W1,
                       const float* __restrict__ W2, const float* __restrict__ W3,
                       ush* __restrict__ H0, ush* __restrict__ H1,
                       ush* __restrict__ H2, ush* __restrict__ H3)
{
  __shared__ float T[32][33];
  const int tx = threadIdx.x, ty = threadIdx.y;    // (32,8)
  const int z = blockIdx.z;
  const float* W = (z==0)?W0:(z==1)?W1:(z==2)?W2:W3;
  ush* H = (z==0)?H0:(z==1)?H1:(z==2)?H2:H3;
  const int k0 = blockIdx.y*32, n0 = blockIdx.x*32;
  #pragma unroll
  for (int i = 0; i < 4; ++i){
    int r = ty + 8*i;
    T[r][tx] = W[(size_t)(k0 + r)*DM + n0 + tx];
  }
  __syncthreads();
  #pragma unroll
  for (int i = 0; i < 4; ++i){
    int r = ty + 8*i;              // n-local
    H[(size_t)(n0 + r)*DM + k0 + tx] = f2bf(T[tx][r]);
  }
}

// ---- fused Q/K/V projection: BK=32, 1-term (W hi), double-buffered LDS via
// global_load_lds width-16 with pre-swizzled per-lane SOURCE addresses.
// 512 threads / 8 waves: each wave owns a 32x64 output quadrant.
// Q/K out plain bf16 (b*16+h, s, dk); V out bf16 transposed (b*16+h, dk, s).
__global__ __launch_bounds__(512) void proj_qkv(
    const ush* __restrict__ xq, const ush* __restrict__ xk, const ush* __restrict__ xv,
    const ush* __restrict__ Wqh, const ush* __restrict__ Wkh, const ush* __restrict__ Wvh,
    const float* __restrict__ bq, const float* __restrict__ bk,
    const float* __restrict__ bv,
    ush* __restrict__ Qb, ush* __restrict__ Kb, ush* __restrict__ Vt)
{
  // staging: 2 bufs x (A 4096 | B 4096) ush = 16384 ush; V-epilogue 8*2176 ush
  __shared__ ush SMEM[17408];

  const int fid = blockIdx.x;
  const int glob = (fid & 7)*96 + (fid >> 3);  // XCD-contiguous chunks of 96
  const int z = glob >> 8, rem = glob & 255;
  const int m0 = (rem >> 3) * 128, n0 = (rem & 7) * 128;

  const ush* A  = (z==0) ? xq  : (z==1) ? xk  : xv;
  const ush* Bh = (z==0) ? Wqh : (z==1) ? Wkh : Wvh;

  const int tid = threadIdx.x;
  const int lane = tid & 63, w = tid >> 6;     // w 0..7
  const int c = lane & 15, g = lane >> 4;
  const int wr = w >> 1, wc = w & 1;           // 4 row-groups x 2 col-groups

  f32x4 acc[2][4];
  #pragma unroll
  for (int i = 0; i < 2; ++i)
    #pragma unroll
    for (int j = 0; j < 4; ++j) acc[i][j] = (f32x4){0.f,0.f,0.f,0.f};

  // GLL source map: wave w instr covers phys rows w*8+(l>>3), chunk j=l&7.
  // XOR key = phys row & 7 = l>>3. Logical row = 2*physrow + (sg>>2),
  // k-offset = (sg&3)*8, sg = (l&7)^(l>>3).
  const int sg = (lane & 7) ^ (lane >> 3);
  const size_t aoff = (size_t)(16*w + 2*(lane >> 3) + (sg >> 2))*DM + (sg & 3)*8;
  const ush* Aab = A  + (size_t)m0*DM;
  const ush* Bhb = Bh + (size_t)n0*DM;
  const int lb = w*512;                        // wave-uniform LDS base (ush)

#define GLL(GP, LIDX) __builtin_amdgcn_global_load_lds( \
    (const __attribute__((address_space(1))) unsigned int*)(GP), \
    (__attribute__((address_space(3))) unsigned int*)(&SMEM[LIDX]), 16, 0, 0)

#define ISSUE_PROJ(BUFO, KT) do{ \
    GLL(Aab + aoff + (KT), (BUFO) + lb); \
    GLL(Bhb + aoff + (KT), (BUFO) + 4096 + lb); \
  }while(0)

  const int csw = (((4*(c & 1) + g) ^ ((c >> 1) & 7)) << 3);

  ISSUE_PROJ(0, 0);
  int cur = 0;
  for (int kt = 0; kt < DM; kt += 32){
    __syncthreads();                       // drains vmcnt -> buf[cur] ready
    if (kt + 32 < DM) ISSUE_PROJ((cur ^ 1)*8192, kt + 32);

    const ush* As  = SMEM + cur*8192;
    const ush* Bhs = As + 4096;

    bf8_t a_h[2];
    #pragma unroll
    for (int fm = 0; fm < 2; ++fm)
      a_h[fm] = *(const bf8_t*)&As[(16*wr + 8*fm + (c>>1))*64 + csw];
    __builtin_amdgcn_s_setprio(1);
    #pragma unroll
    for (int fn = 0; fn < 4; ++fn){
      bf8_t b_h = *(const bf8_t*)&Bhs[(32*wc + 8*fn + (c>>1))*64 + csw];
      #pragma unroll
      for (int fm = 0; fm < 2; ++fm)
        acc[fm][fn] = MFMA16(a_h[fm], b_h, acc[fm][fn]);
    }
    __builtin_amdgcn_s_setprio(0);
    cur ^= 1;
  }
#undef ISSUE_PROJ
#undef GLL

  if (z < 2){
    ush* O = (z==0) ? Qb : Kb;
    const float* bias = (z==0) ? bq : bk;
    #pragma unroll
    for (int fm = 0; fm < 2; ++fm){
      #pragma unroll
      for (int fn = 0; fn < 4; ++fn){
        const int col = n0 + 64*wc + 16*fn + c;
        const float bb = bias[col];
        const int row0 = m0 + 32*wr + 16*fm + 4*g;
        const int hd = col >> 6, d = col & 63;
        #pragma unroll
        for (int r = 0; r < 4; ++r){
          const int row = row0 + r;
          const int b = row >> 10, s = row & 1023;
          O[((size_t)(b*NH + hd)*SS + s)*DKH + d] = f2bf(acc[fm][fn][r] + bb);
        }
      }
    }
  } else {
    // V: transpose wave's 32(s) x 64(d) sub-tile through LDS -> coalesced (d,s)
    __syncthreads();                      // all waves done reading staging LDS
    ush* Vep = SMEM + w*2176;             // 64 rows(d) x 34 cols(s, padded)
    #pragma unroll
    for (int fm = 0; fm < 2; ++fm){
      #pragma unroll
      for (int fn = 0; fn < 4; ++fn){
        const float bb = bv[n0 + 64*wc + 16*fn + c];
        #pragma unroll
        for (int r = 0; r < 4; ++r)
          Vep[(16*fn + c)*34 + 16*fm + 4*g + r] = f2bf(acc[fm][fn][r] + bb);
      }
    }
    const int b = m0 >> 10;
    const int s0 = (m0 & 1023) + 32*wr;
    const int hd = (n0 >> 6) + wc;
    const size_t vbase = ((size_t)(b*NH + hd))*DKH*SS;
    #pragma unroll
    for (int it = 0; it < 4; ++it){
      const int dr = it*16 + (lane >> 2);
      const int sc = (lane & 3)*8;
      uint4 vv = *(const uint4*)&Vep[dr*34 + sc];
      *(uint4*)&Vt[vbase + (size_t)dr*SS + s0 + sc] = vv;
    }
  }
}

// ---- output projection: C = A(bf16) @ Wo^T + bo, 128x64 tile, paired-row LDS
__global__ __launch_bounds__(256) void gemm_out(
    const ush* __restrict__ Abf, const ush* __restrict__ Bth,
    const float* __restrict__ bias, float* __restrict__ outf)
{
  __shared__ ush As[4096], Bs[2048];

  const int fid = blockIdx.x;
  const int glob = (fid & 7)*64 + (fid >> 3);
  const int m0 = (glob >> 4)*128, n0 = (glob & 15)*64;

  const int tid = threadIdx.x;
  const int lane = tid & 63, w = tid >> 6;
  const int c = lane & 15, g = lane >> 4;
  const int wr = w >> 1, wc = w & 1;

  f32x4 acc[4][2];
  #pragma unroll
  for (int i = 0; i < 4; ++i){ acc[i][0] = (f32x4){0,0,0,0}; acc[i][1] = (f32x4){0,0,0,0}; }

  const int prow = tid >> 3, ci = tid & 7;
  const int lr   = 2*prow + (ci >> 2);
  const int koff = (ci & 3) << 3;
  const int ws0  = prow*64 + ((ci ^ (prow & 7)) << 3);
  const int ws1  = ws0 + 32*64;
  const int csw  = (((4*(c & 1) + g) ^ ((c >> 1) & 7)) << 3);

  uint4 ar0, ar1, brr;
  #define ISSUE_OUT(KT) do{ \
    ar0 = *(const uint4*)(Abf + (size_t)(m0 + lr)*DM + (KT) + koff); \
    ar1 = *(const uint4*)(Abf + (size_t)(m0 + lr + 64)*DM + (KT) + koff); \
    brr = *(const uint4*)(Bth + (size_t)(n0 + lr)*DM + (KT) + koff); \
  }while(0)

  ISSUE_OUT(0);
  for (int kt = 0; kt < DM; kt += 32){
    *(uint4*)&As[ws0] = ar0;
    *(uint4*)&As[ws1] = ar1;
    if (lr < 64) *(uint4*)&Bs[ws0] = brr;
    __syncthreads();
    if (kt + 32 < DM) ISSUE_OUT(kt + 32);

    bf8_t a_h[4];
    #pragma unroll
    for (int fm = 0; fm < 4; ++fm)
      a_h[fm] = *(const bf8_t*)&As[(32*wr + 8*fm + (c>>1))*64 + csw];
    #pragma unroll
    for (int fn = 0; fn < 2; ++fn){
      bf8_t b_h = *(const bf8_t*)&Bs[(16*wc + 8*fn + (c>>1))*64 + csw];
      #pragma unroll
      for (int fm = 0; fm < 4; ++fm)
        acc[fm][fn] = MFMA16(a_h[fm], b_h, acc[fm][fn]);
    }
    __syncthreads();
  }
  #undef ISSUE_OUT

  #pragma unroll
  for (int fm = 0; fm < 4; ++fm){
    #pragma unroll
    for (int fn = 0; fn < 2; ++fn){
      const int col = n0 + 32*wc + 16*fn + c;
      const float bb = bias[col];
      const int row0 = m0 + 64*wr + 16*fm + 4*g;
      #pragma unroll
      for (int r = 0; r < 4; ++r)
        outf[(size_t)(row0 + r)*DM + col] = acc[fm][fn][r] + bb;
    }
  }
}

// ---- Stats pass: QBLK=128 (512 thr, 8 waves), KVBLK=64, 1-term QK (Qh),
// plain-bf16 Q/K, double-buffered K LDS (1 barrier/iter), slotted partials.
__global__ __launch_bounds__(512) void attn_stats_mfma(
    const ush* __restrict__ Qb, const ush* __restrict__ Kb,
    float* __restrict__ stats)
{
  __shared__ ush Khs[2*4096];
  __shared__ float red[8][3];
  const int tid = threadIdx.x, lane = tid & 63, w = tid >> 6;   // w 0..7
  const int c = lane & 15, g = lane >> 4;
  const int fid = blockIdx.x;
  const int glob = (fid & 7)*64 + (fid >> 3);     // 512 blocks, XCD-chunked
  const int bh = glob >> 3, qb = glob & 7, q0 = qb*128;

  bf8_t qh[2];
  {
    const ush* qp = Qb + ((size_t)bh*SS + q0 + 16*w + c)*DKH + 8*g;
    qh[0] = *(const bf8_t*)(qp);
    qh[1] = *(const bf8_t*)(qp + 32);
  }

  float ssum = 0.f, rmax = -1e30f, lsum = 0.f, l2sum = 0.f;
  const int rr0 = tid >> 3, ci = tid & 7;         // 64 rows x 8 chunks

  uint4 k0;
  #define ISSUE_ST(KC) do{ \
    k0 = *(const uint4*)(Kb + ((size_t)bh*SS + (KC)*64 + rr0)*DKH + ci*8); \
  }while(0)

  // prologue: tile0 -> buf0; issue tile1; one barrier
  ISSUE_ST(0);
  *(uint4*)&Khs[swz8(rr0, ci)] = k0;
  ISSUE_ST(1);
  __syncthreads();

  for (int kc = 0; kc < 16; ++kc){
    // write tile kc+1 into buf[(kc+1)&1] (prior reads separated by barrier)
    if (kc < 15) *(uint4*)&Khs[((kc+1)&1)*4096 + swz8(rr0, ci)] = k0;
    if (kc < 14) ISSUE_ST(kc + 2);

    const ush* ks = Khs + (kc&1)*4096;
    f32x4 sa[4];
    #pragma unroll
    for (int fn = 0; fn < 4; ++fn) sa[fn] = (f32x4){0.f,0.f,0.f,0.f};
    __builtin_amdgcn_s_setprio(1);
    #pragma unroll
    for (int fn = 0; fn < 4; ++fn){
      #pragma unroll
      for (int ds = 0; ds < 2; ++ds){
        bf8_t ah = *(const bf8_t*)&ks[swz8(16*fn + c, g + 4*ds)];
        sa[fn] = MFMA16(ah, qh[ds], sa[fn]);      // 1-term: Kh . Qh
      }
    }
    __builtin_amdgcn_s_setprio(0);
    #pragma unroll
    for (int fn = 0; fn < 4; ++fn){
      #pragma unroll
      for (int r = 0; r < 4; ++r){
        float s = sa[fn][r] * 0.125f;
        ssum += s;
        rmax = fmaxf(rmax, s);
        float e = exp2f(s * 0.7213475204f);       // exp(s/2); |s|<50 fp32-safe
        lsum += e;
        l2sum = fmaf(e, e, l2sum);
      }
    }
    if (kc < 15) __syncthreads();
  }
  #undef ISSUE_ST

  rmax  = fmaxf(rmax, __shfl_xor(rmax, 16, 64));
  rmax  = fmaxf(rmax, __shfl_xor(rmax, 32, 64));
  lsum  += __shfl_xor(lsum, 16, 64);   lsum  += __shfl_xor(lsum, 32, 64);
  l2sum += __shfl_xor(l2sum, 16, 64);  l2sum += __shfl_xor(l2sum, 32, 64);
  float varc = (l2sum/(lsum*lsum) - (1.0f/1024.f)) * (1.0f/1023.f);
  float a0 = ssum, a1 = rmax * 0.25f, a2 = varc * 0.25f;
  #pragma unroll
  for (int off = 1; off < 64; off <<= 1){
    a0 += __shfl_xor(a0, off, 64);
    a1 += __shfl_xor(a1, off, 64);
    a2 += __shfl_xor(a2, off, 64);
  }
  if (lane == 0){ red[w][0] = a0; red[w][1] = a1; red[w][2] = a2; }
  __syncthreads();
  if (tid == 0){
    float r0 = 0.f, r1 = 0.f, r2 = 0.f;
    #pragma unroll
    for (int i = 0; i < 8; ++i){ r0 += red[i][0]; r1 += red[i][1]; r2 += red[i][2]; }
    float* sp = stats + (size_t)(bh*8 + qb)*4;    // per-block slot, plain stores
    sp[0] = r0; sp[1] = r1; sp[2] = r2;
  }
}

// ---- Flash pass: QBLK=128 (512 thr), KVBLK=64 (16 iters), swapped QK^T
// 1-term (Kh . Qh), plain-bf16 Q/K, exp2, defer-max, swizzled LDS,
// double-buffered K/V (1 barrier/iter). LDS = 48 KB. Time-MLP in prologue.
__global__ __launch_bounds__(512) void attn_flash_mfma(
    const ush* __restrict__ Qb, const ush* __restrict__ Kb,
    const ush* __restrict__ Vt, const float* __restrict__ stats,
    const float* __restrict__ Wt1, const float* __restrict__ bt1,
    const float* __restrict__ Wt2, const float* __restrict__ bt2,
    ush* __restrict__ aout)
{
  __shared__ ush Khs[2*4096], Vts[2*4096], Ps[128*64];
  __shared__ float tshare;
  const int tid = threadIdx.x, lane = tid & 63, w = tid >> 6;   // w 0..7
  const int c = lane & 15, g = lane >> 4;
  const int fid = blockIdx.x;
  const int glob = (fid & 7)*64 + (fid >> 3);     // 512 blocks, XCD-chunked
  const int bh = glob >> 3, q0 = (glob & 7)*128;

  // ---- lane-parallel time-MLP: lane j computes hidden unit j; partials
  // summed from the 8 per-qb slots (deterministic order).
  if (tid < 16){
    const float* sp = stats + (size_t)bh*32;
    float s0 = 0.f, s1 = 0.f, s2 = 0.f;
    #pragma unroll
    for (int qb = 0; qb < 8; ++qb){
      s0 += sp[qb*4 + 0]; s1 += sp[qb*4 + 1]; s2 += sp[qb*4 + 2];
    }
    float mean = fminf(fmaxf(s0 * (1.f/(1024.f*1024.f)), -10.f), 10.f);
    float mx   = fminf(fmaxf(s1 * (1.f/1024.f), -10.f), 10.f);
    float ent  = fminf(fmaxf(s2 * (1.f/1024.f),   0.f),  1.f);
    float h = tanhf(mean*Wt1[tid] + mx*Wt1[16+tid] + ent*Wt1[32+tid] + bt1[tid])
              * Wt2[tid];
    h += __shfl_xor(h, 1, 64);
    h += __shfl_xor(h, 2, 64);
    h += __shfl_xor(h, 4, 64);
    h += __shfl_xor(h, 8, 64);
    if (tid == 0){
      float raw = h + bt2[0];
      float sig = 1.f / (1.f + expf(-raw));
      float t = 0.01f + sig * 1.99f;
      t = fminf(fminf(fmaxf(t, 0.01f), 2.0f), 0.85f);
      tshare = (0.5f / t) * 1.44269504f;          // exp2 domain
    }
  }

  bf8_t qh[2];
  {
    const ush* qp = Qb + ((size_t)bh*SS + q0 + 16*w + c)*DKH + 8*g;
    qh[0] = *(const bf8_t*)(qp);
    qh[1] = *(const bf8_t*)(qp + 32);
  }

  f32x4 o[4];
  #pragma unroll
  for (int i = 0; i < 4; ++i) o[i] = (f32x4){0.f,0.f,0.f,0.f};
  float m = -INFINITY, lpart = 0.f;

  const int rr0 = tid >> 3, ci = tid & 7;         // 64 rows x 8 chunks

  uint4 k0, vr0;
  #define ISSUE_FL(KC) do{ \
    k0  = *(const uint4*)(Kb + ((size_t)bh*SS + (KC)*64 + rr0)*DKH + ci*8); \
    vr0 = *(const uint4*)(Vt + ((size_t)bh*DKH + rr0)*SS + (KC)*64 + ci*8); \
  }while(0)

  // prologue: tile0 -> buf0; issue tile1; one barrier (also publishes tshare)
  ISSUE_FL(0);
  *(uint4*)&Khs[swz8(rr0, ci)] = k0;
  *(uint4*)&Vts[swz8(rr0, ci)] = vr0;
  ISSUE_FL(1);
  __syncthreads();
  const float tsc2 = tshare;

  for (int kc = 0; kc < 16; ++kc){
    // write tile kc+1 into buf[(kc+1)&1]; prior reads separated by barrier
    if (kc < 15){
      *(uint4*)&Khs[((kc+1)&1)*4096 + swz8(rr0, ci)] = k0;
      *(uint4*)&Vts[((kc+1)&1)*4096 + swz8(rr0, ci)] = vr0;
    }
    if (kc < 14) ISSUE_FL(kc + 2);

    const ush* ks = Khs + (kc&1)*4096;
    const ush* vs = Vts + (kc&1)*4096;

    f32x4 sa[4];
    #pragma unroll
    for (int fn = 0; fn < 4; ++fn) sa[fn] = (f32x4){0.f,0.f,0.f,0.f};
    __builtin_amdgcn_s_setprio(1);
    #pragma unroll
    for (int fn = 0; fn < 4; ++fn){
      #pragma unroll
      for (int ds = 0; ds < 2; ++ds){
        bf8_t ah = *(const bf8_t*)&ks[swz8(16*fn + c, g + 4*ds)];
        sa[fn] = MFMA16(ah, qh[ds], sa[fn]);   // 1-term: Kh . Qh
      }
    }
    __builtin_amdgcn_s_setprio(0);

    // lane-local max over own 16 kv; shuffles only in the rare rescale path
    float pmaxr = -1e30f;
    #pragma unroll
    for (int fn = 0; fn < 4; ++fn)
      #pragma unroll
      for (int r = 0; r < 4; ++r) pmaxr = fmaxf(pmaxr, sa[fn][r]);

    if (!__all(pmaxr * tsc2 <= m + 30.f)){     // fires ~once (kc=0)
      pmaxr = fmaxf(pmaxr, __shfl_xor(pmaxr, 16, 64));
      pmaxr = fmaxf(pmaxr, __shfl_xor(pmaxr, 32, 64));
      float pmax = pmaxr * tsc2;
      float mn = fmaxf(m, pmax);
      float sc = exp2f(m - mn);
      m = mn;
      lpart *= sc;
      #pragma unroll
      for (int r = 0; r < 4; ++r){
        float so = __shfl(sc, 4*g + r, 16);    // sc of q-row 4g+r (c'=4g+r)
        #pragma unroll
        for (int fn = 0; fn < 4; ++fn) o[fn][r] *= so;
      }
    }

    const float mneg = -m;
    #pragma unroll
    for (int fn = 0; fn < 4; ++fn){
      float e0 = exp2f(fmaf(sa[fn][0], tsc2, mneg));
      float e1 = exp2f(fmaf(sa[fn][1], tsc2, mneg));
      float e2 = exp2f(fmaf(sa[fn][2], tsc2, mneg));
      float e3 = exp2f(fmaf(sa[fn][3], tsc2, mneg));
      lpart += (e0 + e1) + (e2 + e3);
      uint2 pk;
      pk.x = pk2(e0, e1);
      pk.y = pk2(e2, e3);
      const int q4 = 4*fn + g;
      const int addr = (16*w + c)*64 + ((((q4 >> 1) ^ (c & 7)) << 3)) + (q4 & 1)*4;
      *(uint2*)&Ps[addr] = pk;
    }

    // P rows (16w+c) are wave-local: no barrier needed before PV
    __builtin_amdgcn_s_setprio(1);
    #pragma unroll
    for (int kvs = 0; kvs < 2; ++kvs){
      bf8_t pa = *(const bf8_t*)&Ps[swz8(16*w + c, g + 4*kvs)];
      #pragma unroll
      for (int fn = 0; fn < 4; ++fn){
        bf8_t vb = *(const bf8_t*)&vs[swz8(16*fn + c, g + 4*kvs)];
        o[fn] = MFMA16(pa, vb, o[fn]);
      }
    }
    __builtin_amdgcn_s_setprio(0);
    if (kc < 15) __syncthreads();
  }
  #undef ISSUE_FL

  lpart += __shfl_xor(lpart, 16, 64);
  lpart += __shfl_xor(lpart, 32, 64);
  const int b = bh >> 4, hd = bh & 15;
  #pragma unroll
  for (int r = 0; r < 4; ++r){
    float linv = 1.f / __shfl(lpart, 4*g + r, 16);   // l of q-row 4g+r
    const int q = q0 + 16*w + 4*g + r;
    #pragma unroll
    for (int fn = 0; fn < 4; ++fn)
      aout[((size_t)(b*SS + q))*DM + hd*DKH + 16*fn + c] = f2bf(o[fn][r] * linv);
  }
}

extern "C" void kernel_launch(void* const* d_in, const int* in_sizes, int n_in,
                              void* d_out, int out_size, void* d_ws, size_t ws_size,
                              hipStream_t stream)
{
  const float* query = (const float*)d_in[0];
  const float* key   = (const float*)d_in[1];
  const float* value = (const float*)d_in[2];
  const float* Wq = (const float*)d_in[3];
  const float* bq = (const float*)d_in[4];
  const float* Wk = (const float*)d_in[5];
  const float* bk = (const float*)d_in[6];
  const float* Wv = (const float*)d_in[7];
  const float* bv = (const float*)d_in[8];
  const float* Wo = (const float*)d_in[9];
  const float* bo = (const float*)d_in[10];
  const float* Wt1 = (const float*)d_in[11];
  const float* bt1 = (const float*)d_in[12];
  const float* Wt2 = (const float*)d_in[13];
  const float* bt2 = (const float*)d_in[14];

  const size_t E = (size_t)NB*SS*DM;       // 4,194,304
  const size_t WE = (size_t)DM*DM;

  ush* Qbb = (ush*)d_ws;                   // E ush (plain bf16)
  ush* Kbb = Qbb + E;                      // E ush
  ush* Vtb = Kbb + E;                      // E ush (b*16+h, dk, s)
  ush* Aob = Vtb + E;                      // E ush  -- also aliased as xqb
  ush* xqb = Aob;                          // alias: consumed before Aob written
  ush* xkb = Aob + E;
  ush* xvb = xkb + E;
  ush* Wqh = xvb + E;
  ush* Wkh = Wqh + WE;
  ush* Wvh = Wkh + WE;
  ush* Woh = Wvh + WE;
  float* stats = (float*)(Woh + WE);       // 64 bh x 8 qb x 4 floats = 2048

  xconv<<<dim3(2048, 3), 256, 0, stream>>>(query, key, value, xqb, xkb, xvb);

  dim3 wb(32, 8), wg(32, 32, 4);
  wconv4<<<wg, wb, 0, stream>>>(Wq, Wk, Wv, Wo, Wqh, Wkh, Wvh, Woh);

  proj_qkv<<<768, 512, 0, stream>>>(xqb, xkb, xvb,
      Wqh, Wkh, Wvh, bq, bk, bv, Qbb, Kbb, Vtb);

  attn_stats_mfma<<<512, 512, 0, stream>>>(Qbb, Kbb, stats);
  attn_flash_mfma<<<512, 512, 0, stream>>>(Qbb, Kbb, Vtb, stats,
      Wt1, bt1, Wt2, bt2, Aob);

  gemm_out<<<512, 256, 0, stream>>>(Aob, Woh, bo, (float*)d_out);
}